// Round 1
// baseline (664.296 us; speedup 1.0000x reference)
//
#include <hip/hip_runtime.h>
#include <stdint.h>

#define NA   16000
#define KNN  10
#define NRES 400
#define APR  40
#define NCAT 12
#define BERT 1024
#define FF   128
#define DF1  256
#define DF2  64

__device__ __forceinline__ float bflo(uint32_t u){ return __uint_as_float(u << 16); }
__device__ __forceinline__ float bfhi(uint32_t u){ return __uint_as_float(u & 0xffff0000u); }
__device__ __forceinline__ uint32_t f2bf(float x){
    uint32_t u = __float_as_uint(x);
    return (u + 0x7fffu + ((u >> 16) & 1u)) >> 16;   // round-to-nearest-even bf16
}

// ---------------------------------------------------------------------------
// S = atoms@Wsr1, D = atoms@Wdr1, ACC = atoms@Wv   (K = 12, trivial)
// ---------------------------------------------------------------------------
__global__ void k_atoms3(const float* __restrict__ atoms,
                         const float* __restrict__ Wv, const float* __restrict__ Wsr1,
                         const float* __restrict__ Wdr1,
                         float* __restrict__ ACC, float* __restrict__ S, float* __restrict__ D)
{
    int a = blockIdx.x;
    int f = threadIdx.x;            // 128 threads
    float ar[NCAT];
#pragma unroll
    for (int c = 0; c < NCAT; ++c) ar[c] = atoms[a*NCAT + c];
    float sv = 0.f, ss = 0.f, sd = 0.f;
#pragma unroll
    for (int c = 0; c < NCAT; ++c) {
        sv = fmaf(ar[c], Wv  [c*FF + f], sv);
        ss = fmaf(ar[c], Wsr1[c*FF + f], ss);
        sd = fmaf(ar[c], Wdr1[c*FF + f], sd);
    }
    ACC[(size_t)a*FF + f] = sv;
    S  [(size_t)a*FF + f] = ss;
    D  [(size_t)a*FF + f] = sd;
}

// ---------------------------------------------------------------------------
// C[M,128] (=/+=) A[M,K] @ B[K,128].  BM=64, BN=128, BK=16, 256 threads,
// each thread 4x8 outputs.  M % 64 == 0, K % 16 == 0.
// ---------------------------------------------------------------------------
__global__ void k_gemm(const float* __restrict__ A, const float* __restrict__ B,
                       float* __restrict__ C, int K, int beta)
{
    __shared__ float As[16][68];    // [kk][m], padded
    __shared__ float Bs[16][136];   // [kk][n], padded to 16B-aligned rows
    const int m0  = blockIdx.x * 64;
    const int tid = threadIdx.x;
    const int tx  = tid & 15, ty = tid >> 4;
    float acc[4][8];
#pragma unroll
    for (int r = 0; r < 4; ++r)
#pragma unroll
        for (int c = 0; c < 8; ++c) acc[r][c] = 0.f;

    const int lm = tid >> 2, lq = tid & 3;         // A-tile loader
    const int br = tid >> 5, bc = (tid & 31) * 4;  // B-tile loader

    for (int k0 = 0; k0 < K; k0 += 16) {
        float4 av = *(const float4*)(&A[(size_t)(m0 + lm)*K + k0 + lq*4]);
        As[lq*4+0][lm] = av.x;
        As[lq*4+1][lm] = av.y;
        As[lq*4+2][lm] = av.z;
        As[lq*4+3][lm] = av.w;
#pragma unroll
        for (int rr = 0; rr < 2; ++rr) {
            int r = br + rr*8;
            *(float4*)(&Bs[r][bc]) = *(const float4*)(&B[(size_t)(k0 + r)*FF + bc]);
        }
        __syncthreads();
#pragma unroll
        for (int kk = 0; kk < 16; ++kk) {
            float4 a4 = *(const float4*)(&As[kk][ty*4]);
            float4 b0 = *(const float4*)(&Bs[kk][tx*8]);
            float4 b1 = *(const float4*)(&Bs[kk][tx*8+4]);
            float am[4] = {a4.x,a4.y,a4.z,a4.w};
            float bm[8] = {b0.x,b0.y,b0.z,b0.w,b1.x,b1.y,b1.z,b1.w};
#pragma unroll
            for (int r = 0; r < 4; ++r)
#pragma unroll
                for (int c = 0; c < 8; ++c)
                    acc[r][c] = fmaf(am[r], bm[c], acc[r][c]);
        }
        __syncthreads();
    }
#pragma unroll
    for (int r = 0; r < 4; ++r) {
        float* crow = &C[(size_t)(m0 + ty*4 + r)*FF + tx*8];
        if (beta) {
#pragma unroll
            for (int c = 0; c < 8; ++c) crow[c] += acc[r][c];
        } else {
#pragma unroll
            for (int c = 0; c < 8; ++c) crow[c] = acc[r][c];
        }
    }
}

// ---------------------------------------------------------------------------
// Z = relu(ACC + masked_mean(S, sn) + masked_mean(D, dn))
// ---------------------------------------------------------------------------
__global__ void k_gather_relu(const float* __restrict__ ACC, const float* __restrict__ S,
                              const float* __restrict__ D,
                              const int* __restrict__ sn, const int* __restrict__ dn,
                              float* __restrict__ Z)
{
    int a = blockIdx.x * 2 + (threadIdx.x >> 7);
    int f = threadIdx.x & 127;
    float ssum = 0.f, dsum = 0.f;
    int sc = 0, dc = 0;
#pragma unroll
    for (int n = 0; n < KNN; ++n) {
        int is = sn[a*KNN + n];
        if (is > -1) { ssum += S[(size_t)is*FF + f]; sc++; }
        int id = dn[a*KNN + n];
        if (id > -1) { dsum += D[(size_t)id*FF + f]; dc++; }
    }
    float v = ACC[(size_t)a*FF + f]
            + ssum / (sc > 0 ? (float)sc : 1.f)
            + dsum / (dc > 0 ? (float)dc : 1.f);
    Z[(size_t)a*FF + f] = fmaxf(v, 0.f);
}

// ---------------------------------------------------------------------------
// R[r] = mean over the residue's 40 atoms (res_ids = repeat(arange(400), 40))
// ---------------------------------------------------------------------------
__global__ void k_resmean(const float* __restrict__ Z, float* __restrict__ R)
{
    int r = blockIdx.x, f = threadIdx.x;   // 128 threads
    float s = 0.f;
#pragma unroll 8
    for (int t = 0; t < APR; ++t) s += Z[(size_t)(r*APR + t)*FF + f];
    R[r*FF + f] = s * (1.0f/APR);
}

// ---------------------------------------------------------------------------
// A1[i] = r1[i] @ Wf1[:128,:] + bf1 ;  B1[j] = r2[j] @ Wf1[128:,:]
// ---------------------------------------------------------------------------
__global__ void k_pairprep(const float* __restrict__ R1, const float* __restrict__ R2,
                           const float* __restrict__ Wf1, const float* __restrict__ bf1,
                           float* __restrict__ A1, float* __restrict__ B1)
{
    __shared__ float r1s[FF], r2s[FF];
    int i = blockIdx.x, o = threadIdx.x;   // 256 threads
    if (o < FF) r1s[o] = R1[i*FF + o];
    else        r2s[o-FF] = R2[i*FF + (o-FF)];
    __syncthreads();
    float sa = bf1[o], sb = 0.f;
#pragma unroll 8
    for (int k = 0; k < FF; ++k) {
        sa = fmaf(r1s[k], Wf1[(size_t)k*DF1 + o], sa);
        sb = fmaf(r2s[k], Wf1[(size_t)(FF+k)*DF1 + o], sb);
    }
    A1[(size_t)i*DF1 + o] = sa;
    B1[(size_t)i*DF1 + o] = sb;
}

// ---------------------------------------------------------------------------
// Pack Wf2 [256,64] fp32 -> bf16 pairs:  W2P[kkk*64+f] = 4 k-values for col f
// ---------------------------------------------------------------------------
__global__ void k_packw2(const float* __restrict__ Wf2, uint2* __restrict__ W2P)
{
    int t = blockIdx.x*256 + threadIdx.x;
    if (t >= 64*64) return;
    int kkk = t >> 6, f = t & 63;
    uint32_t q0 = f2bf(Wf2[(size_t)(4*kkk+0)*DF2 + f]);
    uint32_t q1 = f2bf(Wf2[(size_t)(4*kkk+1)*DF2 + f]);
    uint32_t q2 = f2bf(Wf2[(size_t)(4*kkk+2)*DF2 + f]);
    uint32_t q3 = f2bf(Wf2[(size_t)(4*kkk+3)*DF2 + f]);
    W2P[t] = make_uint2(q0 | (q1 << 16), q2 | (q3 << 16));
}

// ---------------------------------------------------------------------------
// Fused pair MLP: out[i*400+j] = relu(relu(A1[i]+B1[j]) @ Wf2 + bf2) @ Wf3 + bf3
// Block tile: 4 i x 4 j = 16 pairs; wave w owns i0+w, lanes = 64 f-columns.
// ---------------------------------------------------------------------------
__global__ void __launch_bounds__(256)
k_pairs(const float* __restrict__ A1, const float* __restrict__ B1,
        const uint2* __restrict__ W2P, const float* __restrict__ bf2,
        const float* __restrict__ Wf3, const float* __restrict__ bf3,
        float* __restrict__ out)
{
    __shared__ float hs[16][256];     // 16 KB
    __shared__ uint2 w2s[4096];       // 32 KB (bf16-packed Wf2)
    const int tid = threadIdx.x;
    const int i0 = blockIdx.x * 4, j0 = blockIdx.y * 4;

    for (int t = tid; t < 4096; t += 256) w2s[t] = W2P[t];

    for (int idx = tid; idx < 16*64; idx += 256) {
        int p = idx >> 6, kq = idx & 63;
        int i = i0 + (p >> 2), j = j0 + (p & 3);
        float4 av = *(const float4*)(&A1[(size_t)i*DF1 + kq*4]);
        float4 bv = *(const float4*)(&B1[(size_t)j*DF1 + kq*4]);
        float4 h;
        h.x = fmaxf(av.x + bv.x, 0.f);
        h.y = fmaxf(av.y + bv.y, 0.f);
        h.z = fmaxf(av.z + bv.z, 0.f);
        h.w = fmaxf(av.w + bv.w, 0.f);
        *(float4*)(&hs[p][kq*4]) = h;
    }
    __syncthreads();

    const int lane = tid & 63, w = tid >> 6;   // wave w -> i = i0+w, pairs p=4w..4w+3
    float acc0=0.f, acc1=0.f, acc2=0.f, acc3=0.f;
#pragma unroll 4
    for (int kkk = 0; kkk < 64; ++kkk) {
        uint2 wv = w2s[kkk*64 + lane];
        float w0l = bflo(wv.x), w1l = bfhi(wv.x);
        float w2l = bflo(wv.y), w3l = bfhi(wv.y);
        float4 h0 = *(const float4*)(&hs[w*4+0][kkk*4]);
        float4 h1 = *(const float4*)(&hs[w*4+1][kkk*4]);
        float4 h2 = *(const float4*)(&hs[w*4+2][kkk*4]);
        float4 h3 = *(const float4*)(&hs[w*4+3][kkk*4]);
        acc0 = fmaf(h0.x,w0l,fmaf(h0.y,w1l,fmaf(h0.z,w2l,fmaf(h0.w,w3l,acc0))));
        acc1 = fmaf(h1.x,w0l,fmaf(h1.y,w1l,fmaf(h1.z,w2l,fmaf(h1.w,w3l,acc1))));
        acc2 = fmaf(h2.x,w0l,fmaf(h2.y,w1l,fmaf(h2.z,w2l,fmaf(h2.w,w3l,acc2))));
        acc3 = fmaf(h3.x,w0l,fmaf(h3.y,w1l,fmaf(h3.z,w2l,fmaf(h3.w,w3l,acc3))));
    }

    const float b2  = bf2[lane];
    const float w3v = Wf3[lane];
    const float b3  = bf3[0];
    float v[4] = {acc0, acc1, acc2, acc3};
#pragma unroll
    for (int jj = 0; jj < 4; ++jj) {
        float val = fmaxf(v[jj] + b2, 0.f) * w3v;
#pragma unroll
        for (int off = 32; off > 0; off >>= 1) val += __shfl_xor(val, off);
        if (lane == 0) out[(size_t)(i0 + w)*NRES + (j0 + jj)] = val + b3;
    }
}

// ---------------------------------------------------------------------------
extern "C" void kernel_launch(void* const* d_in, const int* in_sizes, int n_in,
                              void* d_out, int out_size, void* d_ws, size_t ws_size,
                              hipStream_t stream)
{
    const float* atoms[2]    = {(const float*)d_in[0], (const float*)d_in[5]};
    const float* residues[2] = {(const float*)d_in[1], (const float*)d_in[6]};
    const int*   same[2]     = {(const int*)d_in[2], (const int*)d_in[7]};
    const int*   diff[2]     = {(const int*)d_in[3], (const int*)d_in[8]};
    const float* Wv   = (const float*)d_in[10];
    const float* Wr   = (const float*)d_in[11];
    const float* Wsr1 = (const float*)d_in[12];
    const float* Wdr1 = (const float*)d_in[13];
    const float* Wsv  = (const float*)d_in[14];
    const float* Wsr2 = (const float*)d_in[15];
    const float* Wdr2 = (const float*)d_in[16];
    const float* Wf1  = (const float*)d_in[17];
    const float* bf1  = (const float*)d_in[18];
    const float* Wf2  = (const float*)d_in[19];
    const float* bf2  = (const float*)d_in[20];
    const float* Wf3  = (const float*)d_in[21];
    const float* bf3  = (const float*)d_in[22];

    float* ws  = (float*)d_ws;
    float* ACC = ws;                 // 16000*128
    float* S   = ws + 2048000;
    float* D   = ws + 4096000;
    float* Z   = ws + 6144000;
    float* R12 = ws + 8192000;       // r1 [400*128], r2 [400*128]
    float* A1  = ws + 8294400;       // 400*256
    float* B1  = ws + 8396800;       // 400*256
    uint2* W2P = (uint2*)(ws + 8499200);   // 4096 uint2

    for (int p = 0; p < 2; ++p) {
        float* Rp = R12 + p*51200;
        k_atoms3<<<NA, FF, 0, stream>>>(atoms[p], Wv, Wsr1, Wdr1, ACC, S, D);
        k_gemm<<<NA/64, 256, 0, stream>>>(residues[p], Wr, ACC, BERT, 1);
        k_gather_relu<<<NA/2, 256, 0, stream>>>(ACC, S, D, same[p], diff[p], Z);
        k_gemm<<<NA/64, 256, 0, stream>>>(Z, Wsv,  ACC, FF, 0);
        k_gemm<<<NA/64, 256, 0, stream>>>(Z, Wsr2, S,   FF, 0);
        k_gemm<<<NA/64, 256, 0, stream>>>(Z, Wdr2, D,   FF, 0);
        k_gather_relu<<<NA/2, 256, 0, stream>>>(ACC, S, D, same[p], diff[p], Z);
        k_resmean<<<NRES, FF, 0, stream>>>(Z, Rp);
    }
    k_pairprep<<<NRES, 256, 0, stream>>>(R12, R12 + 51200, Wf1, bf1, A1, B1);
    k_packw2<<<16, 256, 0, stream>>>(Wf2, W2P);
    k_pairs<<<dim3(100, 100), 256, 0, stream>>>(A1, B1, W2P, bf2, Wf3, bf3, (float*)d_out);
}

// Round 2
// 354.039 us; speedup vs baseline: 1.8763x; 1.8763x over previous
//
#include <hip/hip_runtime.h>
#include <stdint.h>

#define NA   16000
#define KNN  10
#define NRES 400
#define APR  40
#define NCAT 12
#define BERT 1024
#define FF   128
#define DF1  256
#define DF2  64

using short8   = __attribute__((ext_vector_type(8))) short;
using floatx4  = __attribute__((ext_vector_type(4))) float;
using ushort4v = __attribute__((ext_vector_type(4))) unsigned short;

__device__ __forceinline__ unsigned short bfc(float v) {
    return __builtin_bit_cast(unsigned short, (__bf16)v);
}
__device__ __forceinline__ void bfsplit(float v, unsigned short& h, unsigned short& l) {
    __bf16 hb = (__bf16)v;
    h = __builtin_bit_cast(unsigned short, hb);
    l = __builtin_bit_cast(unsigned short, (__bf16)(v - (float)hb));
}

// ---------------------------------------------------------------------------
// One-time weight prep: WrT[n][k]=Wr[k][n] hi/lo bf16; Bt3 = [Wsv|Wsr2|Wdr2]^T
// hi/lo; W2T[n][k]=Wf2[k][n] bf16.
// ---------------------------------------------------------------------------
__global__ void k_prep(const float* __restrict__ Wr,
                       const float* __restrict__ Wsv, const float* __restrict__ Wsr2,
                       const float* __restrict__ Wdr2, const float* __restrict__ Wf2,
                       unsigned short* __restrict__ WrT_hi, unsigned short* __restrict__ WrT_lo,
                       unsigned short* __restrict__ Bt3_hi, unsigned short* __restrict__ Bt3_lo,
                       unsigned short* __restrict__ W2T)
{
    int idx = blockIdx.x * 256 + threadIdx.x;
    if (idx < FF * BERT) {                       // 131072
        int n = idx >> 10, k = idx & (BERT - 1);
        bfsplit(Wr[(size_t)k * FF + n], WrT_hi[idx], WrT_lo[idx]);
    } else if (idx < FF * BERT + 3 * FF * FF) {  // +49152
        int i2 = idx - FF * BERT;
        int n = i2 >> 7, k = i2 & 127;
        const float* W = (n < FF) ? Wsv : ((n < 2 * FF) ? Wsr2 : Wdr2);
        bfsplit(W[(size_t)k * FF + (n & 127)], Bt3_hi[i2], Bt3_lo[i2]);
    } else {                                     // +16384
        int i3 = idx - FF * BERT - 3 * FF * FF;
        if (i3 < DF2 * DF1) {
            int n = i3 >> 8, k = i3 & 255;
            W2T[i3] = bfc(Wf2[(size_t)k * DF2 + n]);
        }
    }
}

// ---------------------------------------------------------------------------
// SDZ[a][0:128]=atoms@Wv, [128:256]=atoms@Wsr1, [256:384]=atoms@Wdr1  (K=12)
// ---------------------------------------------------------------------------
__global__ void k_atoms3(const float* __restrict__ atoms,
                         const float* __restrict__ Wv, const float* __restrict__ Wsr1,
                         const float* __restrict__ Wdr1, float* __restrict__ SDZ)
{
    int a = blockIdx.x;
    int f = threadIdx.x;            // 128 threads
    float ar[NCAT];
#pragma unroll
    for (int c = 0; c < NCAT; ++c) ar[c] = atoms[a * NCAT + c];
    float sv = 0.f, ss = 0.f, sd = 0.f;
#pragma unroll
    for (int c = 0; c < NCAT; ++c) {
        sv = fmaf(ar[c], Wv  [c * FF + f], sv);
        ss = fmaf(ar[c], Wsr1[c * FF + f], ss);
        sd = fmaf(ar[c], Wdr1[c * FF + f], sd);
    }
    SDZ[(size_t)a * 384 + f]       = sv;
    SDZ[(size_t)a * 384 + 128 + f] = ss;
    SDZ[(size_t)a * 384 + 256 + f] = sd;
}

// ---------------------------------------------------------------------------
// MFMA GEMM with fp32-accurate bf16 hi/lo split (3-term).
// C[M,N] (=/+=) A[M,K]fp32 @ B[K,N], B given transposed+split: Bt[N][K] bf16.
// BM=64, BN=128, BK=64, 256 threads (4 waves, 2x2 quadrants of 32x64).
// ---------------------------------------------------------------------------
__global__ void __launch_bounds__(256)
k_mfma_gemm(const float* __restrict__ A, int lda,
            const unsigned short* __restrict__ Bth, const unsigned short* __restrict__ Btl,
            float* __restrict__ C, int ldc, int K, int beta)
{
    __shared__ __align__(16) unsigned short sAh[64 * 64], sAl[64 * 64];
    __shared__ __align__(16) unsigned short sBh[128 * 64], sBl[128 * 64];
    const int tid = threadIdx.x, l = tid & 63, w = tid >> 6;
    const int wr = w >> 1, wc = w & 1;
    const int m0 = blockIdx.x * 64, n0 = blockIdx.y * 128;

    floatx4 acc[2][4];
#pragma unroll
    for (int mt = 0; mt < 2; ++mt)
#pragma unroll
        for (int nt = 0; nt < 4; ++nt) acc[mt][nt] = (floatx4){0.f, 0.f, 0.f, 0.f};

    for (int k0 = 0; k0 < K; k0 += 64) {
        if (k0) __syncthreads();
        // ---- stage A tile, fp32 -> bf16 hi/lo, XOR-swizzled ----
#pragma unroll
        for (int pass = 0; pass < 4; ++pass) {
            int row = pass * 16 + (tid >> 4);
            const float4 av = *(const float4*)&A[(size_t)(m0 + row) * lda + k0 + (tid & 15) * 4];
            unsigned short hu[4], lu[4];
            float fv[4] = {av.x, av.y, av.z, av.w};
#pragma unroll
            for (int q = 0; q < 4; ++q) bfsplit(fv[q], hu[q], lu[q]);
            ushort4v hvec = {hu[0], hu[1], hu[2], hu[3]};
            ushort4v lvec = {lu[0], lu[1], lu[2], lu[3]};
            int ba = (row * 128 + (tid & 15) * 8) ^ ((row & 7) << 4);
            *(ushort4v*)((char*)sAh + ba) = hvec;
            *(ushort4v*)((char*)sAl + ba) = lvec;
        }
        // ---- stage B tile (already bf16 hi/lo in global) ----
#pragma unroll
        for (int pass = 0; pass < 4; ++pass) {
            int row = pass * 32 + (tid >> 3);
            size_t gb = (size_t)(n0 + row) * K + k0 + (tid & 7) * 8;
            int ba = (row * 128 + (tid & 7) * 16) ^ ((row & 7) << 4);
            *(uint4*)((char*)sBh + ba) = *(const uint4*)(Bth + gb);
            *(uint4*)((char*)sBl + ba) = *(const uint4*)(Btl + gb);
        }
        __syncthreads();
#pragma unroll
        for (int ks = 0; ks < 2; ++ks) {
            short8 ah[2], al[2], bh[4], bl[4];
            const int kb = ks * 64 + (l >> 4) * 16;
#pragma unroll
            for (int mt = 0; mt < 2; ++mt) {
                int row = wr * 32 + mt * 16 + (l & 15);
                int ba = (row * 128 + kb) ^ ((row & 7) << 4);
                ah[mt] = *(const short8*)((char*)sAh + ba);
                al[mt] = *(const short8*)((char*)sAl + ba);
            }
#pragma unroll
            for (int nt = 0; nt < 4; ++nt) {
                int row = wc * 64 + nt * 16 + (l & 15);
                int ba = (row * 128 + kb) ^ ((row & 7) << 4);
                bh[nt] = *(const short8*)((char*)sBh + ba);
                bl[nt] = *(const short8*)((char*)sBl + ba);
            }
#pragma unroll
            for (int mt = 0; mt < 2; ++mt)
#pragma unroll
                for (int nt = 0; nt < 4; ++nt) {
                    acc[mt][nt] = __builtin_amdgcn_mfma_f32_16x16x32_bf16(ah[mt], bh[nt], acc[mt][nt], 0, 0, 0);
                    acc[mt][nt] = __builtin_amdgcn_mfma_f32_16x16x32_bf16(al[mt], bh[nt], acc[mt][nt], 0, 0, 0);
                    acc[mt][nt] = __builtin_amdgcn_mfma_f32_16x16x32_bf16(ah[mt], bl[nt], acc[mt][nt], 0, 0, 0);
                }
        }
    }
    // ---- epilogue: C/D layout col=lane&15, row=(lane>>4)*4+reg ----
#pragma unroll
    for (int mt = 0; mt < 2; ++mt)
#pragma unroll
        for (int nt = 0; nt < 4; ++nt)
#pragma unroll
            for (int r = 0; r < 4; ++r) {
                int row = m0 + wr * 32 + mt * 16 + (l >> 4) * 4 + r;
                int col = n0 + wc * 64 + nt * 16 + (l & 15);
                float v = acc[mt][nt][r];
                float* cp = &C[(size_t)row * ldc + col];
                if (beta) v += *cp;
                *cp = v;
            }
}

// ---------------------------------------------------------------------------
// Z = relu(SDZ[:,0:128] + masked_mean(SDZ[:,128:256], sn) + masked_mean(SDZ[:,256:384], dn))
// ---------------------------------------------------------------------------
__global__ void k_gather_relu(const float* __restrict__ SDZ,
                              const int* __restrict__ sn, const int* __restrict__ dn,
                              float* __restrict__ Z)
{
    int a = blockIdx.x * 2 + (threadIdx.x >> 7);
    int f = threadIdx.x & 127;
    float ssum = 0.f, dsum = 0.f;
    int sc = 0, dc = 0;
#pragma unroll
    for (int n = 0; n < KNN; ++n) {
        int is = sn[a * KNN + n];
        if (is > -1) { ssum += SDZ[(size_t)is * 384 + 128 + f]; sc++; }
        int id = dn[a * KNN + n];
        if (id > -1) { dsum += SDZ[(size_t)id * 384 + 256 + f]; dc++; }
    }
    float v = SDZ[(size_t)a * 384 + f]
            + ssum / (sc > 0 ? (float)sc : 1.f)
            + dsum / (dc > 0 ? (float)dc : 1.f);
    Z[(size_t)a * FF + f] = fmaxf(v, 0.f);
}

// ---------------------------------------------------------------------------
__global__ void k_resmean(const float* __restrict__ Z, float* __restrict__ R)
{
    int r = blockIdx.x, f = threadIdx.x;   // 128 threads
    float s = 0.f;
#pragma unroll 8
    for (int t = 0; t < APR; ++t) s += Z[(size_t)(r * APR + t) * FF + f];
    R[r * FF + f] = s * (1.0f / APR);
}

// ---------------------------------------------------------------------------
// A1[i] = r1[i] @ Wf1[:128,:] + bf1 ;  B1[j] = r2[j] @ Wf1[128:,:]
// ---------------------------------------------------------------------------
__global__ void k_pairprep(const float* __restrict__ R1, const float* __restrict__ R2,
                           const float* __restrict__ Wf1, const float* __restrict__ bf1,
                           float* __restrict__ A1, float* __restrict__ B1)
{
    __shared__ float r1s[FF], r2s[FF];
    int i = blockIdx.x, o = threadIdx.x;   // 256 threads
    if (o < FF) r1s[o] = R1[i * FF + o];
    else        r2s[o - FF] = R2[i * FF + (o - FF)];
    __syncthreads();
    float sa = bf1[o], sb = 0.f;
#pragma unroll 8
    for (int k = 0; k < FF; ++k) {
        sa = fmaf(r1s[k], Wf1[(size_t)k * DF1 + o], sa);
        sb = fmaf(r2s[k], Wf1[(size_t)(FF + k) * DF1 + o], sb);
    }
    A1[(size_t)i * DF1 + o] = sa;
    B1[(size_t)i * DF1 + o] = sb;
}

// ---------------------------------------------------------------------------
// Pair MLP via MFMA: block = 16 i x 16 j = 256 pairs (M), N=64, K=256.
// H = relu(A1[i]+B1[j]) built in bf16 LDS per 64-wide K chunk.
// ---------------------------------------------------------------------------
__global__ void __launch_bounds__(256)
k_pairs_mfma(const float* __restrict__ A1, const float* __restrict__ B1,
             const unsigned short* __restrict__ W2T,
             const float* __restrict__ bf2, const float* __restrict__ Wf3,
             const float* __restrict__ bf3, float* __restrict__ out)
{
    __shared__ __align__(16) unsigned short sH[256 * 64];   // 32 KB
    __shared__ __align__(16) unsigned short sW[64 * 256];   // 32 KB
    const int tid = threadIdx.x, l = tid & 63, w = tid >> 6;
    const int i0 = blockIdx.x * 16, j0 = blockIdx.y * 16;

    // stage W2T [64][256] bf16, swizzled
    for (int idx = tid; idx < 64 * 32; idx += 256) {
        int row = idx >> 5, c = idx & 31;
        int ba = (row * 512 + c * 16) ^ ((row & 7) << 4);
        *(uint4*)((char*)sW + ba) = *(const uint4*)(W2T + row * 256 + c * 8);
    }

    floatx4 acc[4][4];
#pragma unroll
    for (int mt = 0; mt < 4; ++mt)
#pragma unroll
        for (int nt = 0; nt < 4; ++nt) acc[mt][nt] = (floatx4){0.f, 0.f, 0.f, 0.f};

    float b2r[4], w3r[4];
#pragma unroll
    for (int nt = 0; nt < 4; ++nt) {
        b2r[nt] = bf2[nt * 16 + (l & 15)];
        w3r[nt] = Wf3[nt * 16 + (l & 15)];
    }

    for (int kc = 0; kc < 4; ++kc) {
        __syncthreads();   // previous chunk fully consumed (also fences sW stage)
        // build H[p][0:64] for this chunk, bf16, swizzled
#pragma unroll 4
        for (int pp = 0; pp < 16; ++pp) {
            int p = pp * 16 + (tid >> 4);
            const float4 av = *(const float4*)&A1[(size_t)(i0 + pp) * DF1 + kc * 64 + (tid & 15) * 4];
            const float4 bv = *(const float4*)&B1[(size_t)(j0 + (tid >> 4)) * DF1 + kc * 64 + (tid & 15) * 4];
            ushort4v hv = { bfc(fmaxf(av.x + bv.x, 0.f)), bfc(fmaxf(av.y + bv.y, 0.f)),
                            bfc(fmaxf(av.z + bv.z, 0.f)), bfc(fmaxf(av.w + bv.w, 0.f)) };
            int ba = (p * 128 + (tid & 15) * 8) ^ ((p & 7) << 4);
            *(ushort4v*)((char*)sH + ba) = hv;
        }
        __syncthreads();
#pragma unroll
        for (int ks = 0; ks < 2; ++ks) {
            short8 af[4], bfr[4];
            const int kb = ks * 64 + (l >> 4) * 16;
#pragma unroll
            for (int mt = 0; mt < 4; ++mt) {
                int p = w * 64 + mt * 16 + (l & 15);
                af[mt] = *(const short8*)((char*)sH + ((p * 128 + kb) ^ ((p & 7) << 4)));
            }
            const int kwb = kc * 128 + kb;
#pragma unroll
            for (int nt = 0; nt < 4; ++nt) {
                int n = nt * 16 + (l & 15);
                bfr[nt] = *(const short8*)((char*)sW + ((n * 512 + kwb) ^ ((n & 7) << 4)));
            }
#pragma unroll
            for (int mt = 0; mt < 4; ++mt)
#pragma unroll
                for (int nt = 0; nt < 4; ++nt)
                    acc[mt][nt] = __builtin_amdgcn_mfma_f32_16x16x32_bf16(af[mt], bfr[nt], acc[mt][nt], 0, 0, 0);
        }
    }

    // layer-2: out[p] = sum_n relu(C[p][n]+bf2[n]) * Wf3[n] + bf3
    const float b3 = bf3[0];
#pragma unroll
    for (int mt = 0; mt < 4; ++mt)
#pragma unroll
        for (int r = 0; r < 4; ++r) {
            float s = 0.f;
#pragma unroll
            for (int nt = 0; nt < 4; ++nt)
                s += fmaxf(acc[mt][nt][r] + b2r[nt], 0.f) * w3r[nt];
            s += __shfl_xor(s, 1); s += __shfl_xor(s, 2);
            s += __shfl_xor(s, 4); s += __shfl_xor(s, 8);
            if ((l & 15) == 0) {
                int p = w * 64 + mt * 16 + (l >> 4) * 4 + r;
                out[(size_t)(i0 + (p >> 4)) * NRES + j0 + (p & 15)] = s + b3;
            }
        }
}

// ---------------------------------------------------------------------------
extern "C" void kernel_launch(void* const* d_in, const int* in_sizes, int n_in,
                              void* d_out, int out_size, void* d_ws, size_t ws_size,
                              hipStream_t stream)
{
    const float* atoms[2]    = {(const float*)d_in[0], (const float*)d_in[5]};
    const float* residues[2] = {(const float*)d_in[1], (const float*)d_in[6]};
    const int*   same[2]     = {(const int*)d_in[2], (const int*)d_in[7]};
    const int*   diff[2]     = {(const int*)d_in[3], (const int*)d_in[8]};
    const float* Wv   = (const float*)d_in[10];
    const float* Wr   = (const float*)d_in[11];
    const float* Wsr1 = (const float*)d_in[12];
    const float* Wdr1 = (const float*)d_in[13];
    const float* Wsv  = (const float*)d_in[14];
    const float* Wsr2 = (const float*)d_in[15];
    const float* Wdr2 = (const float*)d_in[16];
    const float* Wf1  = (const float*)d_in[17];
    const float* bf1  = (const float*)d_in[18];
    const float* Wf2  = (const float*)d_in[19];
    const float* bf2  = (const float*)d_in[20];
    const float* Wf3  = (const float*)d_in[21];
    const float* bf3  = (const float*)d_in[22];

    float* ws  = (float*)d_ws;
    float* SDZ = ws;                         // 16000*384 = 6,144,000
    float* Z   = ws + 6144000;               // 16000*128 = 2,048,000
    float* R12 = ws + 8192000;               // 2*400*128 = 102,400
    float* A1  = ws + 8294400;               // 400*256
    float* B1  = ws + 8396800;               // 400*256
    unsigned short* WrT_hi = (unsigned short*)(ws + 8499200);  // 131072 u16
    unsigned short* WrT_lo = (unsigned short*)(ws + 8564736);  // 131072 u16
    unsigned short* Bt3_hi = (unsigned short*)(ws + 8630272);  //  49152 u16
    unsigned short* Bt3_lo = (unsigned short*)(ws + 8654848);  //  49152 u16
    unsigned short* W2T    = (unsigned short*)(ws + 8679424);  //  16384 u16

    k_prep<<<768, 256, 0, stream>>>(Wr, Wsv, Wsr2, Wdr2, Wf2,
                                    WrT_hi, WrT_lo, Bt3_hi, Bt3_lo, W2T);

    for (int p = 0; p < 2; ++p) {
        float* Rp = R12 + p * 51200;
        k_atoms3<<<NA, FF, 0, stream>>>(atoms[p], Wv, Wsr1, Wdr1, SDZ);
        // SDZ[:,0:128] += residues @ Wr
        k_mfma_gemm<<<dim3(NA / 64, 1), 256, 0, stream>>>(residues[p], BERT, WrT_hi, WrT_lo,
                                                          SDZ, 384, BERT, 1);
        k_gather_relu<<<NA / 2, 256, 0, stream>>>(SDZ, same[p], diff[p], Z);
        // SDZ = Z @ [Wsv | Wsr2 | Wdr2]
        k_mfma_gemm<<<dim3(NA / 64, 3), 256, 0, stream>>>(Z, FF, Bt3_hi, Bt3_lo,
                                                          SDZ, 384, FF, 0);
        k_gather_relu<<<NA / 2, 256, 0, stream>>>(SDZ, same[p], diff[p], Z);
        k_resmean<<<NRES, FF, 0, stream>>>(Z, Rp);
    }
    k_pairprep<<<NRES, 256, 0, stream>>>(R12, R12 + 51200, Wf1, bf1, A1, B1);
    k_pairs_mfma<<<dim3(25, 25), 256, 0, stream>>>(A1, B1, W2T, bf2, Wf3, bf3, (float*)d_out);
}

// Round 3
// 211.159 us; speedup vs baseline: 3.1459x; 1.6766x over previous
//
#include <hip/hip_runtime.h>
#include <stdint.h>

#define NA   16000
#define KNN  10
#define NRES 400
#define APR  40
#define NCAT 12
#define BERT 1024
#define FF   128
#define DF1  256
#define DF2  64

using short8   = __attribute__((ext_vector_type(8))) short;
using floatx4  = __attribute__((ext_vector_type(4))) float;
using ushort4v = __attribute__((ext_vector_type(4))) unsigned short;

__device__ __forceinline__ unsigned short bfc(float v) {
    return __builtin_bit_cast(unsigned short, (__bf16)v);
}
__device__ __forceinline__ void bfsplit(float v, unsigned short& h, unsigned short& l) {
    __bf16 hb = (__bf16)v;
    h = __builtin_bit_cast(unsigned short, hb);
    l = __builtin_bit_cast(unsigned short, (__bf16)(v - (float)hb));
}
__device__ __forceinline__ float bflo(uint32_t u){ return __uint_as_float(u << 16); }
__device__ __forceinline__ float bfhi(uint32_t u){ return __uint_as_float(u & 0xffff0000u); }

// ---------------------------------------------------------------------------
// One-time weight prep: WrT[n][k]=Wr[k][n] hi/lo bf16; Bt3 = [Wsv|Wsr2|Wdr2]^T
// hi/lo; W2T[n][k]=Wf2[k][n] bf16.
// ---------------------------------------------------------------------------
__global__ void k_prep(const float* __restrict__ Wr,
                       const float* __restrict__ Wsv, const float* __restrict__ Wsr2,
                       const float* __restrict__ Wdr2, const float* __restrict__ Wf2,
                       unsigned short* __restrict__ WrT_hi, unsigned short* __restrict__ WrT_lo,
                       unsigned short* __restrict__ Bt3_hi, unsigned short* __restrict__ Bt3_lo,
                       unsigned short* __restrict__ W2T)
{
    int idx = blockIdx.x * 256 + threadIdx.x;
    if (idx < FF * BERT) {                       // 131072
        int n = idx >> 10, k = idx & (BERT - 1);
        bfsplit(Wr[(size_t)k * FF + n], WrT_hi[idx], WrT_lo[idx]);
    } else if (idx < FF * BERT + 3 * FF * FF) {  // +49152
        int i2 = idx - FF * BERT;
        int n = i2 >> 7, k = i2 & 127;
        const float* W = (n < FF) ? Wsv : ((n < 2 * FF) ? Wsr2 : Wdr2);
        bfsplit(W[(size_t)k * FF + (n & 127)], Bt3_hi[i2], Bt3_lo[i2]);
    } else {                                     // +16384
        int i3 = idx - FF * BERT - 3 * FF * FF;
        if (i3 < DF2 * DF1) {
            int n = i3 >> 8, k = i3 & 255;
            W2T[i3] = bfc(Wf2[(size_t)k * DF2 + n]);
        }
    }
}

// ---------------------------------------------------------------------------
// ACC[a]=atoms@Wv (fp32), SD[a][0:128]=bf16(atoms@Wsr1), [128:256]=bf16(atoms@Wdr1)
// ---------------------------------------------------------------------------
__global__ void k_atoms3(const float* __restrict__ atoms,
                         const float* __restrict__ Wv, const float* __restrict__ Wsr1,
                         const float* __restrict__ Wdr1,
                         float* __restrict__ ACC, unsigned short* __restrict__ SD)
{
    int a = blockIdx.x * 2 + (threadIdx.x >> 7);
    int f = threadIdx.x & 127;
    float ar[NCAT];
#pragma unroll
    for (int c = 0; c < NCAT; ++c) ar[c] = atoms[a * NCAT + c];
    float sv = 0.f, ss = 0.f, sd = 0.f;
#pragma unroll
    for (int c = 0; c < NCAT; ++c) {
        sv = fmaf(ar[c], Wv  [c * FF + f], sv);
        ss = fmaf(ar[c], Wsr1[c * FF + f], ss);
        sd = fmaf(ar[c], Wdr1[c * FF + f], sd);
    }
    ACC[(size_t)a * FF + f]       = sv;
    SD [(size_t)a * 256 + f]       = bfc(ss);
    SD [(size_t)a * 256 + 128 + f] = bfc(sd);
}

// ---------------------------------------------------------------------------
// MFMA GEMM, fp32-accurate bf16 hi/lo split (3-term).
// A[M,K] fp32, Bt[N_total][K] bf16 hi/lo (transposed), BM=32, BN=128, BK=64,
// 256 threads = 4 waves, wave w owns cols w*32..w*32+31 (2x2 16x16 tiles).
// blockIdx.y==0: Cf[row*128+col] (=/+= per beta).  blockIdx.y>0: bf16 store
// into Cb[row*256 + (y-1)*128 + col].
// ---------------------------------------------------------------------------
__global__ void __launch_bounds__(256)
k_mfma_gemm(const float* __restrict__ A, int lda,
            const unsigned short* __restrict__ Bth, const unsigned short* __restrict__ Btl,
            float* __restrict__ Cf, unsigned short* __restrict__ Cb, int K, int beta)
{
    __shared__ __align__(16) unsigned short sAh[32 * 64], sAl[32 * 64];
    __shared__ __align__(16) unsigned short sBh[128 * 64], sBl[128 * 64];
    const int tid = threadIdx.x, l = tid & 63, w = tid >> 6;
    const int m0 = blockIdx.x * 32, n0 = blockIdx.y * 128;

    floatx4 acc[2][2];
#pragma unroll
    for (int mt = 0; mt < 2; ++mt)
#pragma unroll
        for (int nt = 0; nt < 2; ++nt) acc[mt][nt] = (floatx4){0.f, 0.f, 0.f, 0.f};

    for (int k0 = 0; k0 < K; k0 += 64) {
        if (k0) __syncthreads();
        // ---- stage A tile (32x64), fp32 -> bf16 hi/lo, XOR-swizzled ----
#pragma unroll
        for (int pass = 0; pass < 2; ++pass) {
            int row = pass * 16 + (tid >> 4);
            const float4 av = *(const float4*)&A[(size_t)(m0 + row) * lda + k0 + (tid & 15) * 4];
            unsigned short hu[4], lu[4];
            float fv[4] = {av.x, av.y, av.z, av.w};
#pragma unroll
            for (int q = 0; q < 4; ++q) bfsplit(fv[q], hu[q], lu[q]);
            ushort4v hvec = {hu[0], hu[1], hu[2], hu[3]};
            ushort4v lvec = {lu[0], lu[1], lu[2], lu[3]};
            int ba = (row * 128 + (tid & 15) * 8) ^ ((row & 7) << 4);
            *(ushort4v*)((char*)sAh + ba) = hvec;
            *(ushort4v*)((char*)sAl + ba) = lvec;
        }
        // ---- stage B tile (128x64, already bf16 hi/lo in global) ----
#pragma unroll
        for (int pass = 0; pass < 4; ++pass) {
            int row = pass * 32 + (tid >> 3);
            size_t gb = (size_t)(n0 + row) * K + k0 + (tid & 7) * 8;
            int ba = (row * 128 + (tid & 7) * 16) ^ ((row & 7) << 4);
            *(uint4*)((char*)sBh + ba) = *(const uint4*)(Bth + gb);
            *(uint4*)((char*)sBl + ba) = *(const uint4*)(Btl + gb);
        }
        __syncthreads();
#pragma unroll
        for (int ks = 0; ks < 2; ++ks) {
            short8 ah[2], al[2], bh[2], bl[2];
            const int kb = ks * 64 + (l >> 4) * 16;
#pragma unroll
            for (int mt = 0; mt < 2; ++mt) {
                int row = mt * 16 + (l & 15);
                int ba = (row * 128 + kb) ^ ((row & 7) << 4);
                ah[mt] = *(const short8*)((char*)sAh + ba);
                al[mt] = *(const short8*)((char*)sAl + ba);
            }
#pragma unroll
            for (int nt = 0; nt < 2; ++nt) {
                int row = w * 32 + nt * 16 + (l & 15);
                int ba = (row * 128 + kb) ^ ((row & 7) << 4);
                bh[nt] = *(const short8*)((char*)sBh + ba);
                bl[nt] = *(const short8*)((char*)sBl + ba);
            }
#pragma unroll
            for (int mt = 0; mt < 2; ++mt)
#pragma unroll
                for (int nt = 0; nt < 2; ++nt) {
                    acc[mt][nt] = __builtin_amdgcn_mfma_f32_16x16x32_bf16(ah[mt], bh[nt], acc[mt][nt], 0, 0, 0);
                    acc[mt][nt] = __builtin_amdgcn_mfma_f32_16x16x32_bf16(al[mt], bh[nt], acc[mt][nt], 0, 0, 0);
                    acc[mt][nt] = __builtin_amdgcn_mfma_f32_16x16x32_bf16(ah[mt], bl[nt], acc[mt][nt], 0, 0, 0);
                }
        }
    }
    // ---- epilogue: C/D layout col=lane&15, row=(lane>>4)*4+reg ----
#pragma unroll
    for (int mt = 0; mt < 2; ++mt)
#pragma unroll
        for (int nt = 0; nt < 2; ++nt)
#pragma unroll
            for (int r = 0; r < 4; ++r) {
                int row = m0 + mt * 16 + (l >> 4) * 4 + r;
                int col = w * 32 + nt * 16 + (l & 15);
                float v = acc[mt][nt][r];
                if (blockIdx.y == 0) {
                    float* cp = &Cf[(size_t)row * FF + col];
                    if (beta) v += *cp;
                    *cp = v;
                } else {
                    Cb[(size_t)row * 256 + (blockIdx.y - 1) * 128 + col] = bfc(v);
                }
            }
}

// ---------------------------------------------------------------------------
// Z = relu(ACC + masked_mean(S, sn) + masked_mean(D, dn)); S/D bf16 in SD.
// 16 atoms/block, 16 threads/atom (8 cols each), indices staged in LDS.
// ---------------------------------------------------------------------------
__global__ void __launch_bounds__(256)
k_gather_relu(const float* __restrict__ ACC, const unsigned short* __restrict__ SD,
              const int* __restrict__ sn, const int* __restrict__ dn,
              float* __restrict__ Z)
{
    __shared__ int sIdx[16][20];
    const int tid = threadIdx.x;
    const int a0 = blockIdx.x * 16;
    for (int t = tid; t < 320; t += 256) {
        int at = t / 20, q = t - at * 20;
        sIdx[at][q] = (q < 10) ? sn[(a0 + at) * KNN + q] : dn[(a0 + at) * KNN + q - 10];
    }
    __syncthreads();
    const int at = tid >> 4, c8 = tid & 15;
    const int a = a0 + at;
    float ss[8] = {0,0,0,0,0,0,0,0}, dd[8] = {0,0,0,0,0,0,0,0};
    int sc = 0, dc = 0;
#pragma unroll
    for (int n = 0; n < KNN; ++n) {
        int is = sIdx[at][n];
        if (is > -1) {
            sc++;
            uint4 v = *(const uint4*)&SD[(size_t)is * 256 + c8 * 8];
            uint32_t vv[4] = {v.x, v.y, v.z, v.w};
#pragma unroll
            for (int q = 0; q < 4; ++q) { ss[2*q] += bflo(vv[q]); ss[2*q+1] += bfhi(vv[q]); }
        }
    }
#pragma unroll
    for (int n = 0; n < KNN; ++n) {
        int id = sIdx[at][10 + n];
        if (id > -1) {
            dc++;
            uint4 v = *(const uint4*)&SD[(size_t)id * 256 + 128 + c8 * 8];
            uint32_t vv[4] = {v.x, v.y, v.z, v.w};
#pragma unroll
            for (int q = 0; q < 4; ++q) { dd[2*q] += bflo(vv[q]); dd[2*q+1] += bfhi(vv[q]); }
        }
    }
    const float rs = 1.f / (sc > 0 ? (float)sc : 1.f);
    const float rd = 1.f / (dc > 0 ? (float)dc : 1.f);
    float4 a0v = *(const float4*)&ACC[(size_t)a * FF + c8 * 8];
    float4 a1v = *(const float4*)&ACC[(size_t)a * FF + c8 * 8 + 4];
    float ov[8] = {a0v.x, a0v.y, a0v.z, a0v.w, a1v.x, a1v.y, a1v.z, a1v.w};
    float4 z0, z1;
    z0.x = fmaxf(fmaf(ss[0], rs, fmaf(dd[0], rd, ov[0])), 0.f);
    z0.y = fmaxf(fmaf(ss[1], rs, fmaf(dd[1], rd, ov[1])), 0.f);
    z0.z = fmaxf(fmaf(ss[2], rs, fmaf(dd[2], rd, ov[2])), 0.f);
    z0.w = fmaxf(fmaf(ss[3], rs, fmaf(dd[3], rd, ov[3])), 0.f);
    z1.x = fmaxf(fmaf(ss[4], rs, fmaf(dd[4], rd, ov[4])), 0.f);
    z1.y = fmaxf(fmaf(ss[5], rs, fmaf(dd[5], rd, ov[5])), 0.f);
    z1.z = fmaxf(fmaf(ss[6], rs, fmaf(dd[6], rd, ov[6])), 0.f);
    z1.w = fmaxf(fmaf(ss[7], rs, fmaf(dd[7], rd, ov[7])), 0.f);
    *(float4*)&Z[(size_t)a * FF + c8 * 8]     = z0;
    *(float4*)&Z[(size_t)a * FF + c8 * 8 + 4] = z1;
}

// ---------------------------------------------------------------------------
__global__ void k_resmean(const float* __restrict__ Z, float* __restrict__ R)
{
    int r = blockIdx.x, f = threadIdx.x;   // 128 threads
    float s = 0.f;
#pragma unroll 8
    for (int t = 0; t < APR; ++t) s += Z[(size_t)(r * APR + t) * FF + f];
    R[r * FF + f] = s * (1.0f / APR);
}

// ---------------------------------------------------------------------------
// A1[i] = r1[i] @ Wf1[:128,:] + bf1 ;  B1[j] = r2[j] @ Wf1[128:,:]
// ---------------------------------------------------------------------------
__global__ void k_pairprep(const float* __restrict__ R1, const float* __restrict__ R2,
                           const float* __restrict__ Wf1, const float* __restrict__ bf1,
                           float* __restrict__ A1, float* __restrict__ B1)
{
    __shared__ float r1s[FF], r2s[FF];
    int i = blockIdx.x, o = threadIdx.x;   // 256 threads
    if (o < FF) r1s[o] = R1[i * FF + o];
    else        r2s[o - FF] = R2[i * FF + (o - FF)];
    __syncthreads();
    float sa = bf1[o], sb = 0.f;
#pragma unroll 8
    for (int k = 0; k < FF; ++k) {
        sa = fmaf(r1s[k], Wf1[(size_t)k * DF1 + o], sa);
        sb = fmaf(r2s[k], Wf1[(size_t)(FF + k) * DF1 + o], sb);
    }
    A1[(size_t)i * DF1 + o] = sa;
    B1[(size_t)i * DF1 + o] = sb;
}

// ---------------------------------------------------------------------------
// Pair MLP via MFMA: block = 16 i x 16 j = 256 pairs (M), N=64, K=256.
// ---------------------------------------------------------------------------
__global__ void __launch_bounds__(256)
k_pairs_mfma(const float* __restrict__ A1, const float* __restrict__ B1,
             const unsigned short* __restrict__ W2T,
             const float* __restrict__ bf2, const float* __restrict__ Wf3,
             const float* __restrict__ bf3, float* __restrict__ out)
{
    __shared__ __align__(16) unsigned short sH[256 * 64];   // 32 KB
    __shared__ __align__(16) unsigned short sW[64 * 256];   // 32 KB
    const int tid = threadIdx.x, l = tid & 63, w = tid >> 6;
    const int i0 = blockIdx.x * 16, j0 = blockIdx.y * 16;

    for (int idx = tid; idx < 64 * 32; idx += 256) {
        int row = idx >> 5, c = idx & 31;
        int ba = (row * 512 + c * 16) ^ ((row & 7) << 4);
        *(uint4*)((char*)sW + ba) = *(const uint4*)(W2T + row * 256 + c * 8);
    }

    floatx4 acc[4][4];
#pragma unroll
    for (int mt = 0; mt < 4; ++mt)
#pragma unroll
        for (int nt = 0; nt < 4; ++nt) acc[mt][nt] = (floatx4){0.f, 0.f, 0.f, 0.f};

    float b2r[4], w3r[4];
#pragma unroll
    for (int nt = 0; nt < 4; ++nt) {
        b2r[nt] = bf2[nt * 16 + (l & 15)];
        w3r[nt] = Wf3[nt * 16 + (l & 15)];
    }

    for (int kc = 0; kc < 4; ++kc) {
        __syncthreads();
#pragma unroll 4
        for (int pp = 0; pp < 16; ++pp) {
            int p = pp * 16 + (tid >> 4);
            const float4 av = *(const float4*)&A1[(size_t)(i0 + pp) * DF1 + kc * 64 + (tid & 15) * 4];
            const float4 bv = *(const float4*)&B1[(size_t)(j0 + (tid >> 4)) * DF1 + kc * 64 + (tid & 15) * 4];
            ushort4v hv = { bfc(fmaxf(av.x + bv.x, 0.f)), bfc(fmaxf(av.y + bv.y, 0.f)),
                            bfc(fmaxf(av.z + bv.z, 0.f)), bfc(fmaxf(av.w + bv.w, 0.f)) };
            int ba = (p * 128 + (tid & 15) * 8) ^ ((p & 7) << 4);
            *(ushort4v*)((char*)sH + ba) = hv;
        }
        __syncthreads();
#pragma unroll
        for (int ks = 0; ks < 2; ++ks) {
            short8 af[4], bfr[4];
            const int kb = ks * 64 + (l >> 4) * 16;
#pragma unroll
            for (int mt = 0; mt < 4; ++mt) {
                int p = w * 64 + mt * 16 + (l & 15);
                af[mt] = *(const short8*)((char*)sH + ((p * 128 + kb) ^ ((p & 7) << 4)));
            }
            const int kwb = kc * 128 + kb;
#pragma unroll
            for (int nt = 0; nt < 4; ++nt) {
                int n = nt * 16 + (l & 15);
                bfr[nt] = *(const short8*)((char*)sW + ((n * 512 + kwb) ^ ((n & 7) << 4)));
            }
#pragma unroll
            for (int mt = 0; mt < 4; ++mt)
#pragma unroll
                for (int nt = 0; nt < 4; ++nt)
                    acc[mt][nt] = __builtin_amdgcn_mfma_f32_16x16x32_bf16(af[mt], bfr[nt], acc[mt][nt], 0, 0, 0);
        }
    }

    const float b3 = bf3[0];
#pragma unroll
    for (int mt = 0; mt < 4; ++mt)
#pragma unroll
        for (int r = 0; r < 4; ++r) {
            float s = 0.f;
#pragma unroll
            for (int nt = 0; nt < 4; ++nt)
                s += fmaxf(acc[mt][nt][r] + b2r[nt], 0.f) * w3r[nt];
            s += __shfl_xor(s, 1); s += __shfl_xor(s, 2);
            s += __shfl_xor(s, 4); s += __shfl_xor(s, 8);
            if ((l & 15) == 0) {
                int p = w * 64 + mt * 16 + (l >> 4) * 4 + r;
                out[(size_t)(i0 + (p >> 4)) * NRES + j0 + (p & 15)] = s + b3;
            }
        }
}

// ---------------------------------------------------------------------------
extern "C" void kernel_launch(void* const* d_in, const int* in_sizes, int n_in,
                              void* d_out, int out_size, void* d_ws, size_t ws_size,
                              hipStream_t stream)
{
    const float* atoms[2]    = {(const float*)d_in[0], (const float*)d_in[5]};
    const float* residues[2] = {(const float*)d_in[1], (const float*)d_in[6]};
    const int*   same[2]     = {(const int*)d_in[2], (const int*)d_in[7]};
    const int*   diff[2]     = {(const int*)d_in[3], (const int*)d_in[8]};
    const float* Wv   = (const float*)d_in[10];
    const float* Wr   = (const float*)d_in[11];
    const float* Wsr1 = (const float*)d_in[12];
    const float* Wdr1 = (const float*)d_in[13];
    const float* Wsv  = (const float*)d_in[14];
    const float* Wsr2 = (const float*)d_in[15];
    const float* Wdr2 = (const float*)d_in[16];
    const float* Wf1  = (const float*)d_in[17];
    const float* bf1  = (const float*)d_in[18];
    const float* Wf2  = (const float*)d_in[19];
    const float* bf2  = (const float*)d_in[20];
    const float* Wf3  = (const float*)d_in[21];
    const float* bf3  = (const float*)d_in[22];

    float* ws  = (float*)d_ws;
    float* ACC = ws;                               // 16000*128 fp32
    unsigned short* SD = (unsigned short*)(ws + 2048000);   // 16000*256 bf16 (2,048,000 floats)
    float* Z   = ws + 4096000;                     // 16000*128 fp32
    float* R12 = ws + 6144000;                     // 2*400*128
    float* A1  = ws + 6246400;                     // 400*256
    float* B1  = ws + 6348800;                     // 400*256
    unsigned short* WrT_hi = (unsigned short*)(ws + 6451200);  // 131072 u16
    unsigned short* WrT_lo = (unsigned short*)(ws + 6516736);  // 131072 u16
    unsigned short* Bt3_hi = (unsigned short*)(ws + 6582272);  //  49152 u16
    unsigned short* Bt3_lo = (unsigned short*)(ws + 6606848);  //  49152 u16
    unsigned short* W2T    = (unsigned short*)(ws + 6631424);  //  16384 u16

    k_prep<<<768, 256, 0, stream>>>(Wr, Wsv, Wsr2, Wdr2, Wf2,
                                    WrT_hi, WrT_lo, Bt3_hi, Bt3_lo, W2T);

    for (int p = 0; p < 2; ++p) {
        float* Rp = R12 + p * 51200;
        k_atoms3<<<NA / 2, 256, 0, stream>>>(atoms[p], Wv, Wsr1, Wdr1, ACC, SD);
        // ACC += residues @ Wr
        k_mfma_gemm<<<dim3(NA / 32, 1), 256, 0, stream>>>(residues[p], BERT, WrT_hi, WrT_lo,
                                                          ACC, SD, BERT, 1);
        k_gather_relu<<<NA / 16, 256, 0, stream>>>(ACC, SD, same[p], diff[p], Z);
        // ACC = Z@Wsv ; SD = bf16(Z@[Wsr2|Wdr2])
        k_mfma_gemm<<<dim3(NA / 32, 3), 256, 0, stream>>>(Z, FF, Bt3_hi, Bt3_lo,
                                                          ACC, SD, FF, 0);
        k_gather_relu<<<NA / 16, 256, 0, stream>>>(ACC, SD, same[p], diff[p], Z);
        k_resmean<<<NRES, FF, 0, stream>>>(Z, Rp);
    }
    k_pairprep<<<NRES, 256, 0, stream>>>(R12, R12 + 51200, Wf1, bf1, A1, B1);
    k_pairs_mfma<<<dim3(25, 25), 256, 0, stream>>>(A1, B1, W2T, bf2, Wf3, bf3, (float*)d_out);
}

// Round 4
// 188.723 us; speedup vs baseline: 3.5200x; 1.1189x over previous
//
#include <hip/hip_runtime.h>
#include <stdint.h>

#define NA   16000
#define KNN  10
#define NRES 400
#define APR  40
#define NCAT 12
#define BERT 1024
#define FF   128
#define DF1  256
#define DF2  64

using short8   = __attribute__((ext_vector_type(8))) short;
using floatx4  = __attribute__((ext_vector_type(4))) float;
using ushort4v = __attribute__((ext_vector_type(4))) unsigned short;
using ushort8v = __attribute__((ext_vector_type(8))) unsigned short;

__device__ __forceinline__ unsigned short bfc(float v) {
    return __builtin_bit_cast(unsigned short, (__bf16)v);
}
__device__ __forceinline__ float bflo(uint32_t u){ return __uint_as_float(u << 16); }
__device__ __forceinline__ float bfhi(uint32_t u){ return __uint_as_float(u & 0xffff0000u); }
__device__ __forceinline__ float bfs(unsigned short u){ return __uint_as_float(((uint32_t)u) << 16); }

// async global->LDS, 16B per lane (dest must be wave-uniform base + lane*16)
__device__ __forceinline__ void gload16(void* lds, const void* g) {
    __builtin_amdgcn_global_load_lds(
        (const __attribute__((address_space(1))) uint32_t*)g,
        (__attribute__((address_space(3))) uint32_t*)lds, 16, 0, 0);
}

// ---------------------------------------------------------------------------
// Weight prep.  WrT: [16 tiles][swizzled 128x64 bf16 tile] so that a LINEAR
// global_load_lds of 16384 B produces the XOR-swizzled LDS image directly.
// Within a tile: byte ((n*128 + kq*16) ^ ((n&7)<<4)) holds B[n][kq*8..+8].
// Bt3: same, 3 mats x 2 tiles.  W2T: [64][256] linear bf16.
// ---------------------------------------------------------------------------
__global__ void k_prep(const float* __restrict__ Wr,
                       const float* __restrict__ Wsv, const float* __restrict__ Wsr2,
                       const float* __restrict__ Wdr2, const float* __restrict__ Wf2,
                       unsigned short* __restrict__ WrT, unsigned short* __restrict__ Bt3,
                       unsigned short* __restrict__ W2T)
{
    int idx = blockIdx.x * 256 + threadIdx.x;
    if (idx < 16384) {                       // WrT: 16 tiles x 128 n x 8 kq
        int t = idx >> 10, rem = idx & 1023, n = rem >> 3, kq = rem & 7;
        ushort8v v;
#pragma unroll
        for (int e = 0; e < 8; ++e)
            v[e] = bfc(Wr[(size_t)(t * 64 + kq * 8 + e) * FF + n]);
        int ba = t * 16384 + ((n * 128 + kq * 16) ^ ((n & 7) << 4));
        *(ushort8v*)((char*)WrT + ba) = v;
    } else if (idx < 16384 + 6144) {         // Bt3: 3 mats x 2 tiles x 128 x 8
        int i2 = idx - 16384;
        int m = i2 >> 11, r2 = i2 & 2047;
        int t = r2 >> 10, r3 = r2 & 1023, n = r3 >> 3, kq = r3 & 7;
        const float* W = (m == 0) ? Wsv : ((m == 1) ? Wsr2 : Wdr2);
        ushort8v v;
#pragma unroll
        for (int e = 0; e < 8; ++e)
            v[e] = bfc(W[(size_t)(t * 64 + kq * 8 + e) * FF + n]);
        int ba = (m * 2 + t) * 16384 + ((n * 128 + kq * 16) ^ ((n & 7) << 4));
        *(ushort8v*)((char*)Bt3 + ba) = v;
    } else {                                 // W2T: 16384 elements
        int i3 = idx - 16384 - 6144;
        int n = i3 >> 8, k = i3 & 255;
        W2T[i3] = bfc(Wf2[(size_t)k * DF2 + n]);
    }
}

// ---------------------------------------------------------------------------
// ACC[a]=atoms@Wv (fp32), SD[a][0:128]=bf16(atoms@Wsr1), [128:256]=bf16(atoms@Wdr1)
// ---------------------------------------------------------------------------
__global__ void k_atoms3(const float* __restrict__ atoms,
                         const float* __restrict__ Wv, const float* __restrict__ Wsr1,
                         const float* __restrict__ Wdr1,
                         float* __restrict__ ACC, unsigned short* __restrict__ SD)
{
    int a = blockIdx.x * 2 + (threadIdx.x >> 7);
    int f = threadIdx.x & 127;
    float ar[NCAT];
#pragma unroll
    for (int c = 0; c < NCAT; ++c) ar[c] = atoms[a * NCAT + c];
    float sv = 0.f, ss = 0.f, sd = 0.f;
#pragma unroll
    for (int c = 0; c < NCAT; ++c) {
        sv = fmaf(ar[c], Wv  [c * FF + f], sv);
        ss = fmaf(ar[c], Wsr1[c * FF + f], ss);
        sd = fmaf(ar[c], Wdr1[c * FF + f], sd);
    }
    ACC[(size_t)a * FF + f]        = sv;
    SD [(size_t)a * 256 + f]       = bfc(ss);
    SD [(size_t)a * 256 + 128 + f] = bfc(sd);
}

// ---------------------------------------------------------------------------
// Big GEMM: residues[M=16000,K=1024] @ Wr -> [M,128], K split in 2 chunks.
// blockIdx.y==0: ACC += chunk0 ; blockIdx.y==1: P1 = chunk1.
// BM=32, BN=128, BK=64; B staged via global_load_lds from pre-swizzled WrT.
// ---------------------------------------------------------------------------
__global__ void __launch_bounds__(256)
k_gemm_big(const float* __restrict__ A, const unsigned short* __restrict__ Bsw,
           float* __restrict__ ACC, float* __restrict__ P1)
{
    __shared__ __align__(16) unsigned short sA[32 * 64];    //  4 KB
    __shared__ __align__(16) unsigned short sB[128 * 64];   // 16 KB
    const int tid = threadIdx.x, l = tid & 63, w = tid >> 6;
    const int m0 = blockIdx.x * 32;
    const int tile0 = blockIdx.y * 8;

    floatx4 acc[2][2];
#pragma unroll
    for (int mt = 0; mt < 2; ++mt)
#pragma unroll
        for (int nt = 0; nt < 2; ++nt) acc[mt][nt] = (floatx4){0.f, 0.f, 0.f, 0.f};

    for (int t = 0; t < 8; ++t) {
        if (t) __syncthreads();
        // B: 4x async 16B -> linear LDS (content already swizzled in global)
        const char* bs = (const char*)Bsw + (size_t)(tile0 + t) * 16384 + tid * 16;
        char* bd = (char*)sB + tid * 16;
#pragma unroll
        for (int p = 0; p < 4; ++p) gload16(bd + p * 4096, bs + p * 4096);
        // A: fp32 -> bf16, swizzled reg-stage
#pragma unroll
        for (int pass = 0; pass < 2; ++pass) {
            int row = pass * 16 + (tid >> 4);
            const float4 av = *(const float4*)&A[(size_t)(m0 + row) * BERT + (tile0 + t) * 64 + (tid & 15) * 4];
            ushort4v hv = {bfc(av.x), bfc(av.y), bfc(av.z), bfc(av.w)};
            int ba = (row * 128 + (tid & 15) * 8) ^ ((row & 7) << 4);
            *(ushort4v*)((char*)sA + ba) = hv;
        }
        __syncthreads();   // drains vmcnt (gload) + lgkm (ds_write)
#pragma unroll
        for (int ks = 0; ks < 2; ++ks) {
            short8 ah[2], bh[2];
            const int kb = ks * 64 + (l >> 4) * 16;
#pragma unroll
            for (int mt = 0; mt < 2; ++mt) {
                int row = mt * 16 + (l & 15);
                ah[mt] = *(const short8*)((char*)sA + ((row * 128 + kb) ^ ((row & 7) << 4)));
            }
#pragma unroll
            for (int nt = 0; nt < 2; ++nt) {
                int row = w * 32 + nt * 16 + (l & 15);
                bh[nt] = *(const short8*)((char*)sB + ((row * 128 + kb) ^ ((row & 7) << 4)));
            }
#pragma unroll
            for (int mt = 0; mt < 2; ++mt)
#pragma unroll
                for (int nt = 0; nt < 2; ++nt)
                    acc[mt][nt] = __builtin_amdgcn_mfma_f32_16x16x32_bf16(ah[mt], bh[nt], acc[mt][nt], 0, 0, 0);
        }
    }
    float* C = (blockIdx.y == 0) ? ACC : P1;
    const int addc = (blockIdx.y == 0);
#pragma unroll
    for (int mt = 0; mt < 2; ++mt)
#pragma unroll
        for (int nt = 0; nt < 2; ++nt)
#pragma unroll
            for (int r = 0; r < 4; ++r) {
                int row = m0 + mt * 16 + (l >> 4) * 4 + r;
                int col = w * 32 + nt * 16 + (l & 15);
                float v = acc[mt][nt][r];
                float* cp = &C[(size_t)row * FF + col];
                if (addc) v += *cp;
                *cp = v;
            }
}

// ---------------------------------------------------------------------------
// Layer-2 GEMM: Z[16000,128]bf16(pre-swizzled tiles) @ {Wsv,Wsr2,Wdr2}.
// blockIdx.y = mat: 0 -> ACC fp32 write; 1,2 -> SD bf16 store.
// ---------------------------------------------------------------------------
__global__ void __launch_bounds__(256)
k_gemm_l2(const unsigned short* __restrict__ Zsw, const unsigned short* __restrict__ Bt3,
          float* __restrict__ ACC, unsigned short* __restrict__ SD)
{
    __shared__ __align__(16) unsigned short sA[32 * 64];
    __shared__ __align__(16) unsigned short sB[128 * 64];
    const int tid = threadIdx.x, l = tid & 63, w = tid >> 6;
    const int m0 = blockIdx.x * 32;
    const int mat = blockIdx.y;

    floatx4 acc[2][2];
#pragma unroll
    for (int mt = 0; mt < 2; ++mt)
#pragma unroll
        for (int nt = 0; nt < 2; ++nt) acc[mt][nt] = (floatx4){0.f, 0.f, 0.f, 0.f};

    for (int t = 0; t < 2; ++t) {
        if (t) __syncthreads();
        const char* bs = (const char*)Bt3 + (size_t)(mat * 2 + t) * 16384 + tid * 16;
        char* bd = (char*)sB + tid * 16;
#pragma unroll
        for (int p = 0; p < 4; ++p) gload16(bd + p * 4096, bs + p * 4096);
        gload16((char*)sA + tid * 16,
                (const char*)Zsw + (size_t)((m0 >> 5) * 2 + t) * 4096 + tid * 16);
        __syncthreads();
#pragma unroll
        for (int ks = 0; ks < 2; ++ks) {
            short8 ah[2], bh[2];
            const int kb = ks * 64 + (l >> 4) * 16;
#pragma unroll
            for (int mt = 0; mt < 2; ++mt) {
                int row = mt * 16 + (l & 15);
                ah[mt] = *(const short8*)((char*)sA + ((row * 128 + kb) ^ ((row & 7) << 4)));
            }
#pragma unroll
            for (int nt = 0; nt < 2; ++nt) {
                int row = w * 32 + nt * 16 + (l & 15);
                bh[nt] = *(const short8*)((char*)sB + ((row * 128 + kb) ^ ((row & 7) << 4)));
            }
#pragma unroll
            for (int mt = 0; mt < 2; ++mt)
#pragma unroll
                for (int nt = 0; nt < 2; ++nt)
                    acc[mt][nt] = __builtin_amdgcn_mfma_f32_16x16x32_bf16(ah[mt], bh[nt], acc[mt][nt], 0, 0, 0);
        }
    }
#pragma unroll
    for (int mt = 0; mt < 2; ++mt)
#pragma unroll
        for (int nt = 0; nt < 2; ++nt)
#pragma unroll
            for (int r = 0; r < 4; ++r) {
                int row = m0 + mt * 16 + (l >> 4) * 4 + r;
                int col = w * 32 + nt * 16 + (l & 15);
                float v = acc[mt][nt][r];
                if (mat == 0) ACC[(size_t)row * FF + col] = v;
                else          SD [(size_t)row * 256 + (mat - 1) * FF + col] = bfc(v);
            }
}

// ---------------------------------------------------------------------------
// Z = relu(ACC (+P1) + masked_mean(S) + masked_mean(D)) -> bf16.
// swizzle=1: write pre-swizzled tiles (GEMM A format); else linear [a][128].
// ---------------------------------------------------------------------------
__global__ void __launch_bounds__(256)
k_gather_relu(const float* __restrict__ ACC, const float* __restrict__ P1,
              const unsigned short* __restrict__ SD,
              const int* __restrict__ sn, const int* __restrict__ dn,
              unsigned short* __restrict__ Zout, int addP1, int swizzle)
{
    __shared__ int sIdx[16][20];
    const int tid = threadIdx.x;
    const int a0 = blockIdx.x * 16;
    for (int t = tid; t < 320; t += 256) {
        int at = t / 20, q = t - at * 20;
        sIdx[at][q] = (q < 10) ? sn[(a0 + at) * KNN + q] : dn[(a0 + at) * KNN + q - 10];
    }
    __syncthreads();
    const int at = tid >> 4, c8 = tid & 15;
    const int a = a0 + at;
    float ss[8] = {0,0,0,0,0,0,0,0}, dd[8] = {0,0,0,0,0,0,0,0};
    int sc = 0, dc = 0;
#pragma unroll
    for (int n = 0; n < KNN; ++n) {
        int is = sIdx[at][n];
        if (is > -1) {
            sc++;
            uint4 v = *(const uint4*)&SD[(size_t)is * 256 + c8 * 8];
            uint32_t vv[4] = {v.x, v.y, v.z, v.w};
#pragma unroll
            for (int q = 0; q < 4; ++q) { ss[2*q] += bflo(vv[q]); ss[2*q+1] += bfhi(vv[q]); }
        }
    }
#pragma unroll
    for (int n = 0; n < KNN; ++n) {
        int id = sIdx[at][10 + n];
        if (id > -1) {
            dc++;
            uint4 v = *(const uint4*)&SD[(size_t)id * 256 + 128 + c8 * 8];
            uint32_t vv[4] = {v.x, v.y, v.z, v.w};
#pragma unroll
            for (int q = 0; q < 4; ++q) { dd[2*q] += bflo(vv[q]); dd[2*q+1] += bfhi(vv[q]); }
        }
    }
    const float rs = 1.f / (sc > 0 ? (float)sc : 1.f);
    const float rd = 1.f / (dc > 0 ? (float)dc : 1.f);
    float4 a0v = *(const float4*)&ACC[(size_t)a * FF + c8 * 8];
    float4 a1v = *(const float4*)&ACC[(size_t)a * FF + c8 * 8 + 4];
    float ov[8] = {a0v.x, a0v.y, a0v.z, a0v.w, a1v.x, a1v.y, a1v.z, a1v.w};
    if (addP1) {
        float4 p0v = *(const float4*)&P1[(size_t)a * FF + c8 * 8];
        float4 p1v = *(const float4*)&P1[(size_t)a * FF + c8 * 8 + 4];
        ov[0] += p0v.x; ov[1] += p0v.y; ov[2] += p0v.z; ov[3] += p0v.w;
        ov[4] += p1v.x; ov[5] += p1v.y; ov[6] += p1v.z; ov[7] += p1v.w;
    }
    ushort8v zv;
#pragma unroll
    for (int e = 0; e < 8; ++e)
        zv[e] = bfc(fmaxf(fmaf(ss[e], rs, fmaf(dd[e], rd, ov[e])), 0.f));
    if (swizzle) {
        int ba = ((a >> 5) * 2 + (c8 >> 3)) * 4096
               + (((a & 31) * 128 + (c8 & 7) * 16) ^ ((a & 7) << 4));
        *(ushort8v*)((char*)Zout + ba) = zv;
    } else {
        *(ushort8v*)(Zout + (size_t)a * FF + c8 * 8) = zv;
    }
}

// ---------------------------------------------------------------------------
__global__ void k_resmean(const unsigned short* __restrict__ Zb, float* __restrict__ R)
{
    int r = blockIdx.x, f = threadIdx.x;   // 128 threads
    float s = 0.f;
#pragma unroll 8
    for (int t = 0; t < APR; ++t) s += bfs(Zb[(size_t)(r * APR + t) * FF + f]);
    R[r * FF + f] = s * (1.0f / APR);
}

// ---------------------------------------------------------------------------
// A1[i] = r1[i] @ Wf1[:128,:] + bf1 ;  B1[j] = r2[j] @ Wf1[128:,:]
// ---------------------------------------------------------------------------
__global__ void k_pairprep(const float* __restrict__ R1, const float* __restrict__ R2,
                           const float* __restrict__ Wf1, const float* __restrict__ bf1,
                           float* __restrict__ A1, float* __restrict__ B1)
{
    __shared__ float r1s[FF], r2s[FF];
    int i = blockIdx.x, o = threadIdx.x;   // 256 threads
    if (o < FF) r1s[o] = R1[i * FF + o];
    else        r2s[o - FF] = R2[i * FF + (o - FF)];
    __syncthreads();
    float sa = bf1[o], sb = 0.f;
#pragma unroll 8
    for (int k = 0; k < FF; ++k) {
        sa = fmaf(r1s[k], Wf1[(size_t)k * DF1 + o], sa);
        sb = fmaf(r2s[k], Wf1[(size_t)(FF + k) * DF1 + o], sb);
    }
    A1[(size_t)i * DF1 + o] = sa;
    B1[(size_t)i * DF1 + o] = sb;
}

// ---------------------------------------------------------------------------
// Pair MLP via MFMA: block = 16 i x 16 j = 256 pairs (M), N=64, K=256.
// ---------------------------------------------------------------------------
__global__ void __launch_bounds__(256)
k_pairs_mfma(const float* __restrict__ A1, const float* __restrict__ B1,
             const unsigned short* __restrict__ W2T,
             const float* __restrict__ bf2, const float* __restrict__ Wf3,
             const float* __restrict__ bf3, float* __restrict__ out)
{
    __shared__ __align__(16) unsigned short sH[256 * 64];   // 32 KB
    __shared__ __align__(16) unsigned short sW[64 * 256];   // 32 KB
    const int tid = threadIdx.x, l = tid & 63, w = tid >> 6;
    const int i0 = blockIdx.x * 16, j0 = blockIdx.y * 16;

    for (int idx = tid; idx < 64 * 32; idx += 256) {
        int row = idx >> 5, c = idx & 31;
        int ba = (row * 512 + c * 16) ^ ((row & 7) << 4);
        *(uint4*)((char*)sW + ba) = *(const uint4*)(W2T + row * 256 + c * 8);
    }

    floatx4 acc[4][4];
#pragma unroll
    for (int mt = 0; mt < 4; ++mt)
#pragma unroll
        for (int nt = 0; nt < 4; ++nt) acc[mt][nt] = (floatx4){0.f, 0.f, 0.f, 0.f};

    float b2r[4], w3r[4];
#pragma unroll
    for (int nt = 0; nt < 4; ++nt) {
        b2r[nt] = bf2[nt * 16 + (l & 15)];
        w3r[nt] = Wf3[nt * 16 + (l & 15)];
    }

    for (int kc = 0; kc < 4; ++kc) {
        __syncthreads();
#pragma unroll 4
        for (int pp = 0; pp < 16; ++pp) {
            int p = pp * 16 + (tid >> 4);
            const float4 av = *(const float4*)&A1[(size_t)(i0 + pp) * DF1 + kc * 64 + (tid & 15) * 4];
            const float4 bv = *(const float4*)&B1[(size_t)(j0 + (tid >> 4)) * DF1 + kc * 64 + (tid & 15) * 4];
            ushort4v hv = { bfc(fmaxf(av.x + bv.x, 0.f)), bfc(fmaxf(av.y + bv.y, 0.f)),
                            bfc(fmaxf(av.z + bv.z, 0.f)), bfc(fmaxf(av.w + bv.w, 0.f)) };
            int ba = (p * 128 + (tid & 15) * 8) ^ ((p & 7) << 4);
            *(ushort4v*)((char*)sH + ba) = hv;
        }
        __syncthreads();
#pragma unroll
        for (int ks = 0; ks < 2; ++ks) {
            short8 af[4], bfr[4];
            const int kb = ks * 64 + (l >> 4) * 16;
#pragma unroll
            for (int mt = 0; mt < 4; ++mt) {
                int p = w * 64 + mt * 16 + (l & 15);
                af[mt] = *(const short8*)((char*)sH + ((p * 128 + kb) ^ ((p & 7) << 4)));
            }
            const int kwb = kc * 128 + kb;
#pragma unroll
            for (int nt = 0; nt < 4; ++nt) {
                int n = nt * 16 + (l & 15);
                bfr[nt] = *(const short8*)((char*)sW + ((n * 512 + kwb) ^ ((n & 7) << 4)));
            }
#pragma unroll
            for (int mt = 0; mt < 4; ++mt)
#pragma unroll
                for (int nt = 0; nt < 4; ++nt)
                    acc[mt][nt] = __builtin_amdgcn_mfma_f32_16x16x32_bf16(af[mt], bfr[nt], acc[mt][nt], 0, 0, 0);
        }
    }

    const float b3 = bf3[0];
#pragma unroll
    for (int mt = 0; mt < 4; ++mt)
#pragma unroll
        for (int r = 0; r < 4; ++r) {
            float s = 0.f;
#pragma unroll
            for (int nt = 0; nt < 4; ++nt)
                s += fmaxf(acc[mt][nt][r] + b2r[nt], 0.f) * w3r[nt];
            s += __shfl_xor(s, 1); s += __shfl_xor(s, 2);
            s += __shfl_xor(s, 4); s += __shfl_xor(s, 8);
            if ((l & 15) == 0) {
                int p = w * 64 + mt * 16 + (l >> 4) * 4 + r;
                out[(size_t)(i0 + (p >> 4)) * NRES + j0 + (p & 15)] = s + b3;
            }
        }
}

// ---------------------------------------------------------------------------
extern "C" void kernel_launch(void* const* d_in, const int* in_sizes, int n_in,
                              void* d_out, int out_size, void* d_ws, size_t ws_size,
                              hipStream_t stream)
{
    const float* atoms[2]    = {(const float*)d_in[0], (const float*)d_in[5]};
    const float* residues[2] = {(const float*)d_in[1], (const float*)d_in[6]};
    const int*   same[2]     = {(const int*)d_in[2], (const int*)d_in[7]};
    const int*   diff[2]     = {(const int*)d_in[3], (const int*)d_in[8]};
    const float* Wv   = (const float*)d_in[10];
    const float* Wr   = (const float*)d_in[11];
    const float* Wsr1 = (const float*)d_in[12];
    const float* Wdr1 = (const float*)d_in[13];
    const float* Wsv  = (const float*)d_in[14];
    const float* Wsr2 = (const float*)d_in[15];
    const float* Wdr2 = (const float*)d_in[16];
    const float* Wf1  = (const float*)d_in[17];
    const float* bf1  = (const float*)d_in[18];
    const float* Wf2  = (const float*)d_in[19];
    const float* bf2  = (const float*)d_in[20];
    const float* Wf3  = (const float*)d_in[21];
    const float* bf3  = (const float*)d_in[22];

    float* ws  = (float*)d_ws;
    float* ACC = ws;                                        // 2,048,000 f
    float* P1  = ws + 2048000;                              // 2,048,000 f
    unsigned short* SD  = (unsigned short*)(ws + 4096000);  // 4,096,000 u16
    unsigned short* Zsw = (unsigned short*)(ws + 6144000);  // 2,048,000 u16
    unsigned short* Zb  = (unsigned short*)(ws + 7168000);  // 2,048,000 u16
    float* R12 = ws + 8192000;                              // 102,400 f
    float* A1  = ws + 8294400;                              // 102,400 f
    float* B1  = ws + 8396800;                              // 102,400 f
    unsigned short* WrT = (unsigned short*)(ws + 8499200);  // 131,072 u16
    unsigned short* Bt3 = (unsigned short*)(ws + 8564736);  //  49,152 u16
    unsigned short* W2T = (unsigned short*)(ws + 8589312);  //  16,384 u16

    k_prep<<<152, 256, 0, stream>>>(Wr, Wsv, Wsr2, Wdr2, Wf2, WrT, Bt3, W2T);

    for (int p = 0; p < 2; ++p) {
        float* Rp = R12 + p * 51200;
        k_atoms3<<<NA / 2, 256, 0, stream>>>(atoms[p], Wv, Wsr1, Wdr1, ACC, SD);
        k_gemm_big<<<dim3(NA / 32, 2), 256, 0, stream>>>(residues[p], WrT, ACC, P1);
        k_gather_relu<<<NA / 16, 256, 0, stream>>>(ACC, P1, SD, same[p], diff[p], Zsw, 1, 1);
        k_gemm_l2<<<dim3(NA / 32, 3), 256, 0, stream>>>(Zsw, Bt3, ACC, SD);
        k_gather_relu<<<NA / 16, 256, 0, stream>>>(ACC, P1, SD, same[p], diff[p], Zb, 0, 0);
        k_resmean<<<NRES, FF, 0, stream>>>(Zb, Rp);
    }
    k_pairprep<<<NRES, 256, 0, stream>>>(R12, R12 + 51200, Wf1, bf1, A1, B1);
    k_pairs_mfma<<<dim3(25, 25), 256, 0, stream>>>(A1, B1, W2T, bf2, Wf3, bf3, (float*)d_out);
}

// Round 5
// 145.705 us; speedup vs baseline: 4.5592x; 1.2952x over previous
//
#include <hip/hip_runtime.h>
#include <stdint.h>

#define NA   16000
#define KNN  10
#define NRES 400
#define APR  40
#define NCAT 12
#define BERT 1024
#define FF   128
#define DF1  256
#define DF2  64

using short8   = __attribute__((ext_vector_type(8))) short;
using floatx4  = __attribute__((ext_vector_type(4))) float;
using ushort4v = __attribute__((ext_vector_type(4))) unsigned short;
using ushort8v = __attribute__((ext_vector_type(8))) unsigned short;

__device__ __forceinline__ unsigned short bfc(float v) {
    return __builtin_bit_cast(unsigned short, (__bf16)v);
}
__device__ __forceinline__ float bflo(uint32_t u){ return __uint_as_float(u << 16); }
__device__ __forceinline__ float bfhi(uint32_t u){ return __uint_as_float(u & 0xffff0000u); }
__device__ __forceinline__ float bfs(unsigned short u){ return __uint_as_float(((uint32_t)u) << 16); }

// async global->LDS, 16B per lane (dest must be wave-uniform base + lane*16)
__device__ __forceinline__ void gload16(void* lds, const void* g) {
    __builtin_amdgcn_global_load_lds(
        (const __attribute__((address_space(1))) uint32_t*)g,
        (__attribute__((address_space(3))) uint32_t*)lds, 16, 0, 0);
}

// ---------------------------------------------------------------------------
// Weight prep (unchanged from r4).  WrT: 16 pre-swizzled 128x64 bf16 tiles;
// Bt3: 3 mats x 2 tiles; W2T: [64][256] linear bf16.
// ---------------------------------------------------------------------------
__global__ void k_prep(const float* __restrict__ Wr,
                       const float* __restrict__ Wsv, const float* __restrict__ Wsr2,
                       const float* __restrict__ Wdr2, const float* __restrict__ Wf2,
                       unsigned short* __restrict__ WrT, unsigned short* __restrict__ Bt3,
                       unsigned short* __restrict__ W2T)
{
    int idx = blockIdx.x * 256 + threadIdx.x;
    if (idx < 16384) {
        int t = idx >> 10, rem = idx & 1023, n = rem >> 3, kq = rem & 7;
        ushort8v v;
#pragma unroll
        for (int e = 0; e < 8; ++e)
            v[e] = bfc(Wr[(size_t)(t * 64 + kq * 8 + e) * FF + n]);
        int ba = t * 16384 + ((n * 128 + kq * 16) ^ ((n & 7) << 4));
        *(ushort8v*)((char*)WrT + ba) = v;
    } else if (idx < 16384 + 6144) {
        int i2 = idx - 16384;
        int m = i2 >> 11, r2 = i2 & 2047;
        int t = r2 >> 10, r3 = r2 & 1023, n = r3 >> 3, kq = r3 & 7;
        const float* W = (m == 0) ? Wsv : ((m == 1) ? Wsr2 : Wdr2);
        ushort8v v;
#pragma unroll
        for (int e = 0; e < 8; ++e)
            v[e] = bfc(W[(size_t)(t * 64 + kq * 8 + e) * FF + n]);
        int ba = (m * 2 + t) * 16384 + ((n * 128 + kq * 16) ^ ((n & 7) << 4));
        *(ushort8v*)((char*)Bt3 + ba) = v;
    } else {
        int i3 = idx - 16384 - 6144;
        int n = i3 >> 8, k = i3 & 255;
        W2T[i3] = bfc(Wf2[(size_t)k * DF2 + n]);
    }
}

// ---------------------------------------------------------------------------
// Batched over proteins (blockIdx.y).
// ACC[a]=atoms@Wv (fp32), SD[a][0:128]=bf16(atoms@Wsr1), [128:256]=bf16(atoms@Wdr1)
// ---------------------------------------------------------------------------
__global__ void k_atoms3(const float* __restrict__ atoms0, const float* __restrict__ atoms1,
                         const float* __restrict__ Wv, const float* __restrict__ Wsr1,
                         const float* __restrict__ Wdr1,
                         float* __restrict__ ACC, unsigned short* __restrict__ SD)
{
    const int p = blockIdx.y;
    const float* atoms = p ? atoms1 : atoms0;
    float* ACCp = ACC + (size_t)p * 2048000;
    unsigned short* SDp = SD + (size_t)p * 4096000;
    int a = blockIdx.x * 2 + (threadIdx.x >> 7);
    int f = threadIdx.x & 127;
    float ar[NCAT];
#pragma unroll
    for (int c = 0; c < NCAT; ++c) ar[c] = atoms[a * NCAT + c];
    float sv = 0.f, ss = 0.f, sd = 0.f;
#pragma unroll
    for (int c = 0; c < NCAT; ++c) {
        sv = fmaf(ar[c], Wv  [c * FF + f], sv);
        ss = fmaf(ar[c], Wsr1[c * FF + f], ss);
        sd = fmaf(ar[c], Wdr1[c * FF + f], sd);
    }
    ACCp[(size_t)a * FF + f]        = sv;
    SDp [(size_t)a * 256 + f]       = bfc(ss);
    SDp [(size_t)a * 256 + 128 + f] = bfc(sd);
}

// ---------------------------------------------------------------------------
// Big GEMM: residues[16000,1024] @ Wr -> [16000,128].
// blockIdx: x = m-block (BM=64), y = k-chunk (0/1), z = protein.
// 2-phase double-buffered pipeline: stage t+1 (gload B + reg-load A) BEFORE
// computing t; one barrier per tile.
// ---------------------------------------------------------------------------
__global__ void __launch_bounds__(256)
k_gemm_big(const float* __restrict__ R0, const float* __restrict__ R1,
           const unsigned short* __restrict__ Bsw,
           float* __restrict__ ACC, float* __restrict__ P1)
{
    __shared__ __align__(16) unsigned short sA[2][64 * 64];    // 2 x 8 KB
    __shared__ __align__(16) unsigned short sB[2][128 * 64];   // 2 x 16 KB
    const int tid = threadIdx.x, l = tid & 63, w = tid >> 6;
    const int m0 = blockIdx.x * 64;
    const int chunk = blockIdx.y, tile0 = chunk * 8;
    const float* A = blockIdx.z ? R1 : R0;
    float* C = ((chunk == 0) ? ACC : P1) + (size_t)blockIdx.z * 2048000;

    floatx4 acc[4][2];
#pragma unroll
    for (int mt = 0; mt < 4; ++mt)
#pragma unroll
        for (int nt = 0; nt < 2; ++nt) acc[mt][nt] = (floatx4){0.f, 0.f, 0.f, 0.f};

    const int arow = tid >> 4, acol = (tid & 15) * 4;
    float4 areg[4];

    // prologue: stage t=0 into buf 0
    {
        const char* bs = (const char*)Bsw + (size_t)tile0 * 16384 + tid * 16;
#pragma unroll
        for (int q = 0; q < 4; ++q) gload16((char*)sB[0] + tid * 16 + q * 4096, bs + q * 4096);
#pragma unroll
        for (int pass = 0; pass < 4; ++pass)
            areg[pass] = *(const float4*)&A[(size_t)(m0 + pass * 16 + arow) * BERT + tile0 * 64 + acol];
#pragma unroll
        for (int pass = 0; pass < 4; ++pass) {
            int row = pass * 16 + arow;
            ushort4v hv = {bfc(areg[pass].x), bfc(areg[pass].y), bfc(areg[pass].z), bfc(areg[pass].w)};
            int ba = (row * 128 + acol * 2) ^ ((row & 7) << 4);
            *(ushort4v*)((char*)sA[0] + ba) = hv;
        }
    }
    __syncthreads();

#pragma unroll
    for (int t = 0; t < 8; ++t) {
        const int cur = t & 1, nxt = cur ^ 1;
        if (t < 7) {   // issue next tile's loads before compute
            const char* bs = (const char*)Bsw + (size_t)(tile0 + t + 1) * 16384 + tid * 16;
#pragma unroll
            for (int q = 0; q < 4; ++q) gload16((char*)sB[nxt] + tid * 16 + q * 4096, bs + q * 4096);
#pragma unroll
            for (int pass = 0; pass < 4; ++pass)
                areg[pass] = *(const float4*)&A[(size_t)(m0 + pass * 16 + arow) * BERT + (tile0 + t + 1) * 64 + acol];
        }
        // compute current tile
#pragma unroll
        for (int ks = 0; ks < 2; ++ks) {
            short8 ah[4], bh[2];
            const int kb = ks * 64 + (l >> 4) * 16;
#pragma unroll
            for (int mt = 0; mt < 4; ++mt) {
                int row = mt * 16 + (l & 15);
                ah[mt] = *(const short8*)((char*)sA[cur] + ((row * 128 + kb) ^ ((row & 7) << 4)));
            }
#pragma unroll
            for (int nt = 0; nt < 2; ++nt) {
                int row = w * 32 + nt * 16 + (l & 15);
                bh[nt] = *(const short8*)((char*)sB[cur] + ((row * 128 + kb) ^ ((row & 7) << 4)));
            }
#pragma unroll
            for (int mt = 0; mt < 4; ++mt)
#pragma unroll
                for (int nt = 0; nt < 2; ++nt)
                    acc[mt][nt] = __builtin_amdgcn_mfma_f32_16x16x32_bf16(ah[mt], bh[nt], acc[mt][nt], 0, 0, 0);
        }
        if (t < 7) {   // convert + write A regs into next buffer
#pragma unroll
            for (int pass = 0; pass < 4; ++pass) {
                int row = pass * 16 + arow;
                ushort4v hv = {bfc(areg[pass].x), bfc(areg[pass].y), bfc(areg[pass].z), bfc(areg[pass].w)};
                int ba = (row * 128 + acol * 2) ^ ((row & 7) << 4);
                *(ushort4v*)((char*)sA[nxt] + ba) = hv;
            }
        }
        __syncthreads();
    }

    const int addc = (chunk == 0);
#pragma unroll
    for (int mt = 0; mt < 4; ++mt)
#pragma unroll
        for (int nt = 0; nt < 2; ++nt)
#pragma unroll
            for (int r = 0; r < 4; ++r) {
                int row = m0 + mt * 16 + (l >> 4) * 4 + r;
                int col = w * 32 + nt * 16 + (l & 15);
                float v = acc[mt][nt][r];
                float* cp = &C[(size_t)row * FF + col];
                if (addc) v += *cp;
                *cp = v;
            }
}

// ---------------------------------------------------------------------------
// Layer-2 GEMM: Z(pre-swizzled bf16 tiles) @ {Wsv,Wsr2,Wdr2}.  K=128, both
// k-tiles staged up-front (single barrier).  blockIdx: x=m, y=mat, z=protein.
// ---------------------------------------------------------------------------
__global__ void __launch_bounds__(256)
k_gemm_l2(const unsigned short* __restrict__ Zsw, const unsigned short* __restrict__ Bt3,
          float* __restrict__ ACC, unsigned short* __restrict__ SD)
{
    __shared__ __align__(16) unsigned short sA[2][32 * 64];   // 2 x 4 KB
    __shared__ __align__(16) unsigned short sB[2][128 * 64];  // 2 x 16 KB
    const int tid = threadIdx.x, l = tid & 63, w = tid >> 6;
    const int m0 = blockIdx.x * 32;
    const int mat = blockIdx.y, p = blockIdx.z;
    const unsigned short* Zp = Zsw + (size_t)p * 2048000;

    floatx4 acc[2][2];
#pragma unroll
    for (int mt = 0; mt < 2; ++mt)
#pragma unroll
        for (int nt = 0; nt < 2; ++nt) acc[mt][nt] = (floatx4){0.f, 0.f, 0.f, 0.f};

#pragma unroll
    for (int t = 0; t < 2; ++t) {
        const char* bs = (const char*)Bt3 + (size_t)(mat * 2 + t) * 16384 + tid * 16;
#pragma unroll
        for (int q = 0; q < 4; ++q) gload16((char*)sB[t] + tid * 16 + q * 4096, bs + q * 4096);
        gload16((char*)sA[t] + tid * 16,
                (const char*)Zp + (size_t)((m0 >> 5) * 2 + t) * 4096 + tid * 16);
    }
    __syncthreads();

#pragma unroll
    for (int t = 0; t < 2; ++t)
#pragma unroll
        for (int ks = 0; ks < 2; ++ks) {
            short8 ah[2], bh[2];
            const int kb = ks * 64 + (l >> 4) * 16;
#pragma unroll
            for (int mt = 0; mt < 2; ++mt) {
                int row = mt * 16 + (l & 15);
                ah[mt] = *(const short8*)((char*)sA[t] + ((row * 128 + kb) ^ ((row & 7) << 4)));
            }
#pragma unroll
            for (int nt = 0; nt < 2; ++nt) {
                int row = w * 32 + nt * 16 + (l & 15);
                bh[nt] = *(const short8*)((char*)sB[t] + ((row * 128 + kb) ^ ((row & 7) << 4)));
            }
#pragma unroll
            for (int mt = 0; mt < 2; ++mt)
#pragma unroll
                for (int nt = 0; nt < 2; ++nt)
                    acc[mt][nt] = __builtin_amdgcn_mfma_f32_16x16x32_bf16(ah[mt], bh[nt], acc[mt][nt], 0, 0, 0);
        }

    float* ACCp = ACC + (size_t)p * 2048000;
    unsigned short* SDp = (unsigned short*)SD + (size_t)p * 4096000;
#pragma unroll
    for (int mt = 0; mt < 2; ++mt)
#pragma unroll
        for (int nt = 0; nt < 2; ++nt)
#pragma unroll
            for (int r = 0; r < 4; ++r) {
                int row = m0 + mt * 16 + (l >> 4) * 4 + r;
                int col = w * 32 + nt * 16 + (l & 15);
                float v = acc[mt][nt][r];
                if (mat == 0) ACCp[(size_t)row * FF + col] = v;
                else          SDp [(size_t)row * 256 + (mat - 1) * FF + col] = bfc(v);
            }
}

// ---------------------------------------------------------------------------
// Z = relu(ACC (+P1) + masked_mean(S) + masked_mean(D)) -> bf16.
// Batched over proteins via blockIdx.y.
// ---------------------------------------------------------------------------
__global__ void __launch_bounds__(256)
k_gather_relu(const float* __restrict__ ACC, const float* __restrict__ P1,
              const unsigned short* __restrict__ SD,
              const int* __restrict__ sn0, const int* __restrict__ dn0,
              const int* __restrict__ sn1, const int* __restrict__ dn1,
              unsigned short* __restrict__ Zout, int addP1, int swizzle)
{
    __shared__ int sIdx[16][20];
    const int tid = threadIdx.x;
    const int p = blockIdx.y;
    const int a0 = blockIdx.x * 16;
    const int* sn = p ? sn1 : sn0;
    const int* dn = p ? dn1 : dn0;
    const float* ACCp = ACC + (size_t)p * 2048000;
    const float* P1p  = P1  + (size_t)p * 2048000;
    const unsigned short* SDp = SD + (size_t)p * 4096000;
    unsigned short* Zp = Zout + (size_t)p * 2048000;

    for (int t = tid; t < 320; t += 256) {
        int at = t / 20, q = t - at * 20;
        sIdx[at][q] = (q < 10) ? sn[(a0 + at) * KNN + q] : dn[(a0 + at) * KNN + q - 10];
    }
    __syncthreads();
    const int at = tid >> 4, c8 = tid & 15;
    const int a = a0 + at;
    float ss[8] = {0,0,0,0,0,0,0,0}, dd[8] = {0,0,0,0,0,0,0,0};
    int sc = 0, dc = 0;
#pragma unroll
    for (int n = 0; n < KNN; ++n) {
        int is = sIdx[at][n];
        if (is > -1) {
            sc++;
            uint4 v = *(const uint4*)&SDp[(size_t)is * 256 + c8 * 8];
            uint32_t vv[4] = {v.x, v.y, v.z, v.w};
#pragma unroll
            for (int q = 0; q < 4; ++q) { ss[2*q] += bflo(vv[q]); ss[2*q+1] += bfhi(vv[q]); }
        }
    }
#pragma unroll
    for (int n = 0; n < KNN; ++n) {
        int id = sIdx[at][10 + n];
        if (id > -1) {
            dc++;
            uint4 v = *(const uint4*)&SDp[(size_t)id * 256 + 128 + c8 * 8];
            uint32_t vv[4] = {v.x, v.y, v.z, v.w};
#pragma unroll
            for (int q = 0; q < 4; ++q) { dd[2*q] += bflo(vv[q]); dd[2*q+1] += bfhi(vv[q]); }
        }
    }
    const float rs = 1.f / (sc > 0 ? (float)sc : 1.f);
    const float rd = 1.f / (dc > 0 ? (float)dc : 1.f);
    float4 a0v = *(const float4*)&ACCp[(size_t)a * FF + c8 * 8];
    float4 a1v = *(const float4*)&ACCp[(size_t)a * FF + c8 * 8 + 4];
    float ov[8] = {a0v.x, a0v.y, a0v.z, a0v.w, a1v.x, a1v.y, a1v.z, a1v.w};
    if (addP1) {
        float4 p0v = *(const float4*)&P1p[(size_t)a * FF + c8 * 8];
        float4 p1v = *(const float4*)&P1p[(size_t)a * FF + c8 * 8 + 4];
        ov[0] += p0v.x; ov[1] += p0v.y; ov[2] += p0v.z; ov[3] += p0v.w;
        ov[4] += p1v.x; ov[5] += p1v.y; ov[6] += p1v.z; ov[7] += p1v.w;
    }
    ushort8v zv;
#pragma unroll
    for (int e = 0; e < 8; ++e)
        zv[e] = bfc(fmaxf(fmaf(ss[e], rs, fmaf(dd[e], rd, ov[e])), 0.f));
    if (swizzle) {
        int ba = ((a >> 5) * 2 + (c8 >> 3)) * 4096
               + (((a & 31) * 128 + (c8 & 7) * 16) ^ ((a & 7) << 4));
        *(ushort8v*)((char*)Zp + ba) = zv;
    } else {
        *(ushort8v*)(Zp + (size_t)a * FF + c8 * 8) = zv;
    }
}

// ---------------------------------------------------------------------------
__global__ void k_resmean(const unsigned short* __restrict__ Zb, float* __restrict__ R12)
{
    const int p = blockIdx.y;
    const unsigned short* Zp = Zb + (size_t)p * 2048000;
    float* R = R12 + (size_t)p * 51200;
    int r = blockIdx.x, f = threadIdx.x;   // 128 threads
    float s = 0.f;
#pragma unroll 8
    for (int t = 0; t < APR; ++t) s += bfs(Zp[(size_t)(r * APR + t) * FF + f]);
    R[r * FF + f] = s * (1.0f / APR);
}

// ---------------------------------------------------------------------------
// A1[i] = r1[i] @ Wf1[:128,:] + bf1 ;  B1[j] = r2[j] @ Wf1[128:,:]
// ---------------------------------------------------------------------------
__global__ void k_pairprep(const float* __restrict__ R1, const float* __restrict__ R2,
                           const float* __restrict__ Wf1, const float* __restrict__ bf1,
                           float* __restrict__ A1, float* __restrict__ B1)
{
    __shared__ float r1s[FF], r2s[FF];
    int i = blockIdx.x, o = threadIdx.x;   // 256 threads
    if (o < FF) r1s[o] = R1[i * FF + o];
    else        r2s[o - FF] = R2[i * FF + (o - FF)];
    __syncthreads();
    float sa = bf1[o], sb = 0.f;
#pragma unroll 8
    for (int k = 0; k < FF; ++k) {
        sa = fmaf(r1s[k], Wf1[(size_t)k * DF1 + o], sa);
        sb = fmaf(r2s[k], Wf1[(size_t)(FF + k) * DF1 + o], sb);
    }
    A1[(size_t)i * DF1 + o] = sa;
    B1[(size_t)i * DF1 + o] = sb;
}

// ---------------------------------------------------------------------------
// Pair MLP via MFMA, register-built H (no H LDS round-trip, no inner barriers).
// Block = 16 i x 16 j = 256 pairs; wave w + m-tile mt -> i = i0 + w*4 + mt
// (wave-uniform), lane's A-frag row = j = j0 + (l&15).
// H[p][k] = relu(A1[i][k] + B1[j][k]) built per-lane from LDS fp32 tiles.
// ---------------------------------------------------------------------------
__global__ void __launch_bounds__(256)
k_pairs_mfma(const float* __restrict__ A1, const float* __restrict__ B1,
             const unsigned short* __restrict__ W2T,
             const float* __restrict__ bf2, const float* __restrict__ Wf3,
             const float* __restrict__ bf3, float* __restrict__ out)
{
    __shared__ __align__(16) float sA1[16 * 256];            // 16 KB linear
    __shared__ __align__(16) float sB1[16 * 256];            // 16 KB, XOR (row&7)<<5
    __shared__ __align__(16) unsigned short sW[64 * 256];    // 32 KB, XOR (n&7)<<4
    const int tid = threadIdx.x, l = tid & 63, w = tid >> 6;
    const int i0 = blockIdx.x * 16, j0 = blockIdx.y * 16;

    // stage W2T swizzled
    for (int idx = tid; idx < 64 * 32; idx += 256) {
        int row = idx >> 5, c = idx & 31;
        int ba = (row * 512 + c * 16) ^ ((row & 7) << 4);
        *(uint4*)((char*)sW + ba) = *(const uint4*)(W2T + row * 256 + c * 8);
    }
    // stage A1/B1 tiles (16 rows x 256 f32 each)
    {
        int row = tid >> 4;
#pragma unroll
        for (int pass = 0; pass < 4; ++pass) {
            int coff = pass * 64 + (tid & 15) * 4;
            *(float4*)((char*)sA1 + row * 1024 + coff * 4) =
                *(const float4*)&A1[(size_t)(i0 + row) * DF1 + coff];
            int bb = (row * 1024 + coff * 4) ^ ((row & 7) << 5);
            *(float4*)((char*)sB1 + bb) =
                *(const float4*)&B1[(size_t)(j0 + row) * DF1 + coff];
        }
    }
    __syncthreads();

    floatx4 acc[4][4];
#pragma unroll
    for (int mt = 0; mt < 4; ++mt)
#pragma unroll
        for (int nt = 0; nt < 4; ++nt) acc[mt][nt] = (floatx4){0.f, 0.f, 0.f, 0.f};

    float b2r[4], w3r[4];
#pragma unroll
    for (int nt = 0; nt < 4; ++nt) {
        b2r[nt] = bf2[nt * 16 + (l & 15)];
        w3r[nt] = Wf3[nt * 16 + (l & 15)];
    }

    const int rB = l & 15, kq = l >> 4;
#pragma unroll
    for (int kc = 0; kc < 4; ++kc)
#pragma unroll
        for (int ks = 0; ks < 2; ++ks) {
            const int kfb = (kc * 64 + ks * 32 + kq * 8) * 4;   // byte offset of lane's 8 floats
            // B1 row = l&15 (per-lane), XOR-swizzled
            float4 b1a = *(const float4*)((char*)sB1 + ((rB * 1024 + kfb)      ^ ((rB & 7) << 5)));
            float4 b1b = *(const float4*)((char*)sB1 + ((rB * 1024 + kfb + 16) ^ ((rB & 7) << 5)));
            short8 afr[4];
#pragma unroll
            for (int mt = 0; mt < 4; ++mt) {
                int rA = w * 4 + mt;   // wave-uniform row -> broadcast reads
                float4 a1a = *(const float4*)((char*)sA1 + rA * 1024 + kfb);
                float4 a1b = *(const float4*)((char*)sA1 + rA * 1024 + kfb + 16);
                short8 hv;
                hv[0] = (short)bfc(fmaxf(a1a.x + b1a.x, 0.f));
                hv[1] = (short)bfc(fmaxf(a1a.y + b1a.y, 0.f));
                hv[2] = (short)bfc(fmaxf(a1a.z + b1a.z, 0.f));
                hv[3] = (short)bfc(fmaxf(a1a.w + b1a.w, 0.f));
                hv[4] = (short)bfc(fmaxf(a1b.x + b1b.x, 0.f));
                hv[5] = (short)bfc(fmaxf(a1b.y + b1b.y, 0.f));
                hv[6] = (short)bfc(fmaxf(a1b.z + b1b.z, 0.f));
                hv[7] = (short)bfc(fmaxf(a1b.w + b1b.w, 0.f));
                afr[mt] = hv;
            }
            const int kwb = kc * 128 + ks * 64 + kq * 16;   // byte offset in W rows
            short8 bfr[4];
#pragma unroll
            for (int nt = 0; nt < 4; ++nt) {
                int n = nt * 16 + (l & 15);
                bfr[nt] = *(const short8*)((char*)sW + ((n * 512 + kwb) ^ ((n & 7) << 4)));
            }
#pragma unroll
            for (int mt = 0; mt < 4; ++mt)
#pragma unroll
                for (int nt = 0; nt < 4; ++nt)
                    acc[mt][nt] = __builtin_amdgcn_mfma_f32_16x16x32_bf16(afr[mt], bfr[nt], acc[mt][nt], 0, 0, 0);
        }

    const float b3 = bf3[0];
#pragma unroll
    for (int mt = 0; mt < 4; ++mt)
#pragma unroll
        for (int r = 0; r < 4; ++r) {
            float s = 0.f;
#pragma unroll
            for (int nt = 0; nt < 4; ++nt)
                s += fmaxf(acc[mt][nt][r] + b2r[nt], 0.f) * w3r[nt];
            s += __shfl_xor(s, 1); s += __shfl_xor(s, 2);
            s += __shfl_xor(s, 4); s += __shfl_xor(s, 8);
            if ((l & 15) == 0) {
                int p = w * 64 + mt * 16 + (l >> 4) * 4 + r;
                out[(size_t)(i0 + (p >> 4)) * NRES + j0 + (p & 15)] = s + b3;
            }
        }
}

// ---------------------------------------------------------------------------
extern "C" void kernel_launch(void* const* d_in, const int* in_sizes, int n_in,
                              void* d_out, int out_size, void* d_ws, size_t ws_size,
                              hipStream_t stream)
{
    const float* atoms0    = (const float*)d_in[0];
    const float* residues0 = (const float*)d_in[1];
    const int*   same0     = (const int*)d_in[2];
    const int*   diff0     = (const int*)d_in[3];
    const float* atoms1    = (const float*)d_in[5];
    const float* residues1 = (const float*)d_in[6];
    const int*   same1     = (const int*)d_in[7];
    const int*   diff1     = (const int*)d_in[8];
    const float* Wv   = (const float*)d_in[10];
    const float* Wr   = (const float*)d_in[11];
    const float* Wsr1 = (const float*)d_in[12];
    const float* Wdr1 = (const float*)d_in[13];
    const float* Wsv  = (const float*)d_in[14];
    const float* Wsr2 = (const float*)d_in[15];
    const float* Wdr2 = (const float*)d_in[16];
    const float* Wf1  = (const float*)d_in[17];
    const float* bf1  = (const float*)d_in[18];
    const float* Wf2  = (const float*)d_in[19];
    const float* bf2  = (const float*)d_in[20];
    const float* Wf3  = (const float*)d_in[21];
    const float* bf3  = (const float*)d_in[22];

    float* ws  = (float*)d_ws;
    float* ACC = ws;                                         // 2 x 2,048,000 f
    float* P1  = ws + 4096000;                               // 2 x 2,048,000 f
    unsigned short* SD  = (unsigned short*)(ws + 8192000);   // 2 x 4,096,000 u16
    unsigned short* Zsw = (unsigned short*)(ws + 12288000);  // 2 x 2,048,000 u16
    unsigned short* Zb  = (unsigned short*)(ws + 14336000);  // 2 x 2,048,000 u16
    float* R12 = ws + 16384000;                              // 2 x 51,200 f
    float* A1  = ws + 16486400;                              // 102,400 f
    float* B1  = ws + 16588800;                              // 102,400 f
    unsigned short* WrT = (unsigned short*)(ws + 16691200);  // 131,072 u16
    unsigned short* Bt3 = (unsigned short*)(ws + 16756736);  //  49,152 u16
    unsigned short* W2T = (unsigned short*)(ws + 16781312);  //  16,384 u16

    k_prep<<<152, 256, 0, stream>>>(Wr, Wsv, Wsr2, Wdr2, Wf2, WrT, Bt3, W2T);
    k_atoms3<<<dim3(NA / 2, 2), 256, 0, stream>>>(atoms0, atoms1, Wv, Wsr1, Wdr1, ACC, SD);
    k_gemm_big<<<dim3(NA / 64, 2, 2), 256, 0, stream>>>(residues0, residues1, WrT, ACC, P1);
    k_gather_relu<<<dim3(NA / 16, 2), 256, 0, stream>>>(ACC, P1, SD, same0, diff0, same1, diff1,
                                                        Zsw, 1, 1);
    k_gemm_l2<<<dim3(NA / 32, 3, 2), 256, 0, stream>>>(Zsw, Bt3, ACC, SD);
    k_gather_relu<<<dim3(NA / 16, 2), 256, 0, stream>>>(ACC, P1, SD, same0, diff0, same1, diff1,
                                                        Zb, 0, 0);
    k_resmean<<<dim3(NRES, 2), 128, 0, stream>>>(Zb, R12);
    k_pairprep<<<NRES, 256, 0, stream>>>(R12, R12 + 51200, Wf1, bf1, A1, B1);
    k_pairs_mfma<<<dim3(25, 25), 256, 0, stream>>>(A1, B1, W2T, bf2, Wf3, bf3, (float*)d_out);
}

// Round 6
// 145.650 us; speedup vs baseline: 4.5609x; 1.0004x over previous
//
#include <hip/hip_runtime.h>
#include <stdint.h>

#define NA   16000
#define KNN  10
#define NRES 400
#define APR  40
#define NCAT 12
#define BERT 1024
#define FF   128
#define DF1  256
#define DF2  64

using short8   = __attribute__((ext_vector_type(8))) short;
using floatx4  = __attribute__((ext_vector_type(4))) float;
using ushort4v = __attribute__((ext_vector_type(4))) unsigned short;
using ushort8v = __attribute__((ext_vector_type(8))) unsigned short;

__device__ __forceinline__ unsigned short bfc(float v) {
    return __builtin_bit_cast(unsigned short, (__bf16)v);
}
__device__ __forceinline__ float bflo(uint32_t u){ return __uint_as_float(u << 16); }
__device__ __forceinline__ float bfhi(uint32_t u){ return __uint_as_float(u & 0xffff0000u); }
__device__ __forceinline__ float bfs(unsigned short u){ return __uint_as_float(((uint32_t)u) << 16); }

// async global->LDS, 16B per lane (dest must be wave-uniform base + lane*16)
__device__ __forceinline__ void gload16(void* lds, const void* g) {
    __builtin_amdgcn_global_load_lds(
        (const __attribute__((address_space(1))) uint32_t*)g,
        (__attribute__((address_space(3))) uint32_t*)lds, 16, 0, 0);
}

// ---------------------------------------------------------------------------
// Weight prep.  WrT: 16 pre-swizzled 128x64 bf16 tiles (linear gload -> LDS
// image is already XOR-swizzled); Bt3: 3 mats x 2 tiles; W2T: [64][256] bf16.
// ---------------------------------------------------------------------------
__global__ void k_prep(const float* __restrict__ Wr,
                       const float* __restrict__ Wsv, const float* __restrict__ Wsr2,
                       const float* __restrict__ Wdr2, const float* __restrict__ Wf2,
                       unsigned short* __restrict__ WrT, unsigned short* __restrict__ Bt3,
                       unsigned short* __restrict__ W2T)
{
    int idx = blockIdx.x * 256 + threadIdx.x;
    if (idx < 16384) {
        int t = idx >> 10, rem = idx & 1023, n = rem >> 3, kq = rem & 7;
        ushort8v v;
#pragma unroll
        for (int e = 0; e < 8; ++e)
            v[e] = bfc(Wr[(size_t)(t * 64 + kq * 8 + e) * FF + n]);
        int ba = t * 16384 + ((n * 128 + kq * 16) ^ ((n & 7) << 4));
        *(ushort8v*)((char*)WrT + ba) = v;
    } else if (idx < 16384 + 6144) {
        int i2 = idx - 16384;
        int m = i2 >> 11, r2 = i2 & 2047;
        int t = r2 >> 10, r3 = r2 & 1023, n = r3 >> 3, kq = r3 & 7;
        const float* W = (m == 0) ? Wsv : ((m == 1) ? Wsr2 : Wdr2);
        ushort8v v;
#pragma unroll
        for (int e = 0; e < 8; ++e)
            v[e] = bfc(W[(size_t)(t * 64 + kq * 8 + e) * FF + n]);
        int ba = (m * 2 + t) * 16384 + ((n * 128 + kq * 16) ^ ((n & 7) << 4));
        *(ushort8v*)((char*)Bt3 + ba) = v;
    } else {
        int i3 = idx - 16384 - 6144;
        int n = i3 >> 8, k = i3 & 255;
        W2T[i3] = bfc(Wf2[(size_t)k * DF2 + n]);
    }
}

// ---------------------------------------------------------------------------
// SD[a][0:128]=bf16(atoms@Wsr1), [128:256]=bf16(atoms@Wdr1).  Batched (y=p).
// ---------------------------------------------------------------------------
__global__ void k_atomsSD(const float* __restrict__ atoms0, const float* __restrict__ atoms1,
                          const float* __restrict__ Wsr1, const float* __restrict__ Wdr1,
                          unsigned short* __restrict__ SD)
{
    const int p = blockIdx.y;
    const float* atoms = p ? atoms1 : atoms0;
    unsigned short* SDp = SD + (size_t)p * 4096000;
    int a = blockIdx.x * 2 + (threadIdx.x >> 7);
    int f = threadIdx.x & 127;
    float ar[NCAT];
#pragma unroll
    for (int c = 0; c < NCAT; ++c) ar[c] = atoms[a * NCAT + c];
    float ss = 0.f, sd = 0.f;
#pragma unroll
    for (int c = 0; c < NCAT; ++c) {
        ss = fmaf(ar[c], Wsr1[c * FF + f], ss);
        sd = fmaf(ar[c], Wdr1[c * FF + f], sd);
    }
    SDp[(size_t)a * 256 + f]       = bfc(ss);
    SDp[(size_t)a * 256 + 128 + f] = bfc(sd);
}

// ---------------------------------------------------------------------------
// Big GEMM: residues[16000,1024] @ Wr -> ACC[16000,128] fp32 (plain store).
// BM=64, BK=64, 16 K-tiles.  3-stage pipeline, counted vmcnt, raw s_barrier:
//   per tile t: issue B(t+1) gloads | issue A(t+2) reg loads | MFMA tile t |
//   ds_write A(t+1) (compiler-counted wait) | s_waitcnt vmcnt(4) lgkmcnt(0) |
//   s_barrier.  A-loads get ~2 tile-periods of latency; vmem never drains to 0.
// ---------------------------------------------------------------------------
__global__ void __launch_bounds__(256)
k_gemm_big(const float* __restrict__ R0, const float* __restrict__ R1,
           const unsigned short* __restrict__ Bsw, float* __restrict__ OUT)
{
    __shared__ __align__(16) unsigned short sA[2][64 * 64];    // 2 x 8 KB
    __shared__ __align__(16) unsigned short sB[2][128 * 64];   // 2 x 16 KB
    const int tid = threadIdx.x, l = tid & 63, w = tid >> 6;
    const int m0 = blockIdx.x * 64;
    const float* A = blockIdx.y ? R1 : R0;
    float* C = OUT + (size_t)blockIdx.y * 2048000;

    floatx4 acc[4][2];
#pragma unroll
    for (int mt = 0; mt < 4; ++mt)
#pragma unroll
        for (int nt = 0; nt < 2; ++nt) acc[mt][nt] = (floatx4){0.f, 0.f, 0.f, 0.f};

    const int arow = tid >> 4, acol = (tid & 15) * 4;

    // ---- prologue ----
    {
        float4 a0r[4];
#pragma unroll
        for (int pass = 0; pass < 4; ++pass)
            a0r[pass] = *(const float4*)&A[(size_t)(m0 + pass * 16 + arow) * BERT + acol];
#pragma unroll
        for (int pass = 0; pass < 4; ++pass) {
            int row = pass * 16 + arow;
            ushort4v hv = {bfc(a0r[pass].x), bfc(a0r[pass].y), bfc(a0r[pass].z), bfc(a0r[pass].w)};
            *(ushort4v*)((char*)sA[0] + ((row * 128 + (tid & 15) * 8) ^ ((row & 7) << 4))) = hv;
        }
    }
    __builtin_amdgcn_sched_barrier(0);
    {
        const char* bs = (const char*)Bsw + tid * 16;
        char* bd = (char*)sB[0] + tid * 16;
#pragma unroll
        for (int q = 0; q < 4; ++q) gload16(bd + q * 4096, bs + q * 4096);
    }
    __builtin_amdgcn_sched_barrier(0);
    float4 aP[4], aQ[4];
#pragma unroll
    for (int pass = 0; pass < 4; ++pass)
        aP[pass] = *(const float4*)&A[(size_t)(m0 + pass * 16 + arow) * BERT + 64 + acol];
    __builtin_amdgcn_sched_barrier(0);
    asm volatile("s_waitcnt vmcnt(4) lgkmcnt(0)" ::: "memory");
    __builtin_amdgcn_sched_barrier(0);
    __builtin_amdgcn_s_barrier();
    __builtin_amdgcn_sched_barrier(0);

    // ---- main loop ----
    auto step = [&](int t, int cur, float4* aC, float4* aN) {
        const int nxt = cur ^ 1;
        // issue B(t+1) -> sB[nxt] (clamped dummy at t=15 keeps counts uniform)
        {
            int bt = (t + 1 < 16) ? t + 1 : 15;
            const char* bs = (const char*)Bsw + (size_t)bt * 16384 + tid * 16;
            char* bd = (char*)sB[nxt] + tid * 16;
#pragma unroll
            for (int q = 0; q < 4; ++q) gload16(bd + q * 4096, bs + q * 4096);
        }
        __builtin_amdgcn_sched_barrier(0);
        // issue A(t+2) reg loads (clamped)
        {
            int at2 = (t + 2 < 16) ? t + 2 : 15;
#pragma unroll
            for (int pass = 0; pass < 4; ++pass)
                aN[pass] = *(const float4*)&A[(size_t)(m0 + pass * 16 + arow) * BERT + at2 * 64 + acol];
        }
        __builtin_amdgcn_sched_barrier(0);
        // compute tile t
#pragma unroll
        for (int ks = 0; ks < 2; ++ks) {
            short8 ah[4], bh[2];
            const int kb = ks * 64 + (l >> 4) * 16;
#pragma unroll
            for (int mt = 0; mt < 4; ++mt) {
                int row = mt * 16 + (l & 15);
                ah[mt] = *(const short8*)((char*)sA[cur] + ((row * 128 + kb) ^ ((row & 7) << 4)));
            }
#pragma unroll
            for (int nt = 0; nt < 2; ++nt) {
                int row = w * 32 + nt * 16 + (l & 15);
                bh[nt] = *(const short8*)((char*)sB[cur] + ((row * 128 + kb) ^ ((row & 7) << 4)));
            }
#pragma unroll
            for (int mt = 0; mt < 4; ++mt)
#pragma unroll
                for (int nt = 0; nt < 2; ++nt)
                    acc[mt][nt] = __builtin_amdgcn_mfma_f32_16x16x32_bf16(ah[mt], bh[nt], acc[mt][nt], 0, 0, 0);
        }
        __builtin_amdgcn_sched_barrier(0);
        // ds_write A(t+1) -> sA[nxt] (compiler inserts counted vmcnt for aC)
#pragma unroll
        for (int pass = 0; pass < 4; ++pass) {
            int row = pass * 16 + arow;
            ushort4v hv = {bfc(aC[pass].x), bfc(aC[pass].y), bfc(aC[pass].z), bfc(aC[pass].w)};
            *(ushort4v*)((char*)sA[nxt] + ((row * 128 + (tid & 15) * 8) ^ ((row & 7) << 4))) = hv;
        }
        __builtin_amdgcn_sched_barrier(0);
        asm volatile("s_waitcnt vmcnt(4) lgkmcnt(0)" ::: "memory");
        __builtin_amdgcn_sched_barrier(0);
        __builtin_amdgcn_s_barrier();
        __builtin_amdgcn_sched_barrier(0);
    };
#pragma unroll
    for (int tt = 0; tt < 8; ++tt) {
        step(2 * tt,     0, aP, aQ);
        step(2 * tt + 1, 1, aQ, aP);
    }

    // ---- epilogue ----
#pragma unroll
    for (int mt = 0; mt < 4; ++mt)
#pragma unroll
        for (int nt = 0; nt < 2; ++nt)
#pragma unroll
            for (int r = 0; r < 4; ++r) {
                int row = m0 + mt * 16 + (l >> 4) * 4 + r;
                int col = w * 32 + nt * 16 + (l & 15);
                C[(size_t)row * FF + col] = acc[mt][nt][r];
            }
}

// ---------------------------------------------------------------------------
// Layer-2 GEMM: Z(pre-swizzled bf16 tiles) @ {Wsv,Wsr2,Wdr2}.  K=128, both
// k-tiles staged up-front (single barrier).  blockIdx: x=m, y=mat, z=protein.
// ---------------------------------------------------------------------------
__global__ void __launch_bounds__(256)
k_gemm_l2(const unsigned short* __restrict__ Zsw, const unsigned short* __restrict__ Bt3,
          float* __restrict__ ACC, unsigned short* __restrict__ SD)
{
    __shared__ __align__(16) unsigned short sA[2][32 * 64];   // 2 x 4 KB
    __shared__ __align__(16) unsigned short sB[2][128 * 64];  // 2 x 16 KB
    const int tid = threadIdx.x, l = tid & 63, w = tid >> 6;
    const int m0 = blockIdx.x * 32;
    const int mat = blockIdx.y, p = blockIdx.z;
    const unsigned short* Zp = Zsw + (size_t)p * 2048000;

    floatx4 acc[2][2];
#pragma unroll
    for (int mt = 0; mt < 2; ++mt)
#pragma unroll
        for (int nt = 0; nt < 2; ++nt) acc[mt][nt] = (floatx4){0.f, 0.f, 0.f, 0.f};

#pragma unroll
    for (int t = 0; t < 2; ++t) {
        const char* bs = (const char*)Bt3 + (size_t)(mat * 2 + t) * 16384 + tid * 16;
#pragma unroll
        for (int q = 0; q < 4; ++q) gload16((char*)sB[t] + tid * 16 + q * 4096, bs + q * 4096);
        gload16((char*)sA[t] + tid * 16,
                (const char*)Zp + (size_t)((m0 >> 5) * 2 + t) * 4096 + tid * 16);
    }
    __syncthreads();

#pragma unroll
    for (int t = 0; t < 2; ++t)
#pragma unroll
        for (int ks = 0; ks < 2; ++ks) {
            short8 ah[2], bh[2];
            const int kb = ks * 64 + (l >> 4) * 16;
#pragma unroll
            for (int mt = 0; mt < 2; ++mt) {
                int row = mt * 16 + (l & 15);
                ah[mt] = *(const short8*)((char*)sA[t] + ((row * 128 + kb) ^ ((row & 7) << 4)));
            }
#pragma unroll
            for (int nt = 0; nt < 2; ++nt) {
                int row = w * 32 + nt * 16 + (l & 15);
                bh[nt] = *(const short8*)((char*)sB[t] + ((row * 128 + kb) ^ ((row & 7) << 4)));
            }
#pragma unroll
            for (int mt = 0; mt < 2; ++mt)
#pragma unroll
                for (int nt = 0; nt < 2; ++nt)
                    acc[mt][nt] = __builtin_amdgcn_mfma_f32_16x16x32_bf16(ah[mt], bh[nt], acc[mt][nt], 0, 0, 0);
        }

    float* ACCp = ACC + (size_t)p * 2048000;
    unsigned short* SDp = (unsigned short*)SD + (size_t)p * 4096000;
#pragma unroll
    for (int mt = 0; mt < 2; ++mt)
#pragma unroll
        for (int nt = 0; nt < 2; ++nt)
#pragma unroll
            for (int r = 0; r < 4; ++r) {
                int row = m0 + mt * 16 + (l >> 4) * 4 + r;
                int col = w * 32 + nt * 16 + (l & 15);
                float v = acc[mt][nt][r];
                if (mat == 0) ACCp[(size_t)row * FF + col] = v;
                else          SDp [(size_t)row * 256 + (mat - 1) * FF + col] = bfc(v);
            }
}

// ---------------------------------------------------------------------------
// Z = relu(ACC [+ atoms@Wv] + masked_mean(S) + masked_mean(D)) -> bf16.
// addAtoms: compute the fp32 atoms@Wv term inline (Wv + atom rows in LDS).
// ---------------------------------------------------------------------------
__global__ void __launch_bounds__(256)
k_gather_relu(const float* __restrict__ ACC, const unsigned short* __restrict__ SD,
              const int* __restrict__ sn0, const int* __restrict__ dn0,
              const int* __restrict__ sn1, const int* __restrict__ dn1,
              const float* __restrict__ atoms0, const float* __restrict__ atoms1,
              const float* __restrict__ Wv,
              unsigned short* __restrict__ Zout, int addAtoms, int swizzle)
{
    __shared__ int sIdx[16][20];
    __shared__ float sWv[NCAT * FF];   // 6 KB
    __shared__ float sAt[16 * NCAT];   // 768 B
    const int tid = threadIdx.x;
    const int p = blockIdx.y;
    const int a0 = blockIdx.x * 16;
    const int* sn = p ? sn1 : sn0;
    const int* dn = p ? dn1 : dn0;
    const float* ACCp = ACC + (size_t)p * 2048000;
    const unsigned short* SDp = SD + (size_t)p * 4096000;
    unsigned short* Zp = Zout + (size_t)p * 2048000;

    for (int t = tid; t < 320; t += 256) {
        int at = t / 20, q = t - at * 20;
        sIdx[at][q] = (q < 10) ? sn[(a0 + at) * KNN + q] : dn[(a0 + at) * KNN + q - 10];
    }
    if (addAtoms) {
        const float* atoms = p ? atoms1 : atoms0;
        for (int i = tid; i < 384; i += 256)
            ((float4*)sWv)[i] = ((const float4*)Wv)[i];
        if (tid < 48) {
            int at = tid / 3, q = tid - at * 3;
            *(float4*)&sAt[at * NCAT + q * 4] =
                *(const float4*)&atoms[(size_t)(a0 + at) * NCAT + q * 4];
        }
    }
    __syncthreads();
    const int at = tid >> 4, c8 = tid & 15;
    const int a = a0 + at;
    float ss[8] = {0,0,0,0,0,0,0,0}, dd[8] = {0,0,0,0,0,0,0,0};
    int sc = 0, dc = 0;
#pragma unroll
    for (int n = 0; n < KNN; ++n) {
        int is = sIdx[at][n];
        if (is > -1) {
            sc++;
            uint4 v = *(const uint4*)&SDp[(size_t)is * 256 + c8 * 8];
            uint32_t vv[4] = {v.x, v.y, v.z, v.w};
#pragma unroll
            for (int q = 0; q < 4; ++q) { ss[2*q] += bflo(vv[q]); ss[2*q+1] += bfhi(vv[q]); }
        }
    }
#pragma unroll
    for (int n = 0; n < KNN; ++n) {
        int id = sIdx[at][10 + n];
        if (id > -1) {
            dc++;
            uint4 v = *(const uint4*)&SDp[(size_t)id * 256 + 128 + c8 * 8];
            uint32_t vv[4] = {v.x, v.y, v.z, v.w};
#pragma unroll
            for (int q = 0; q < 4; ++q) { dd[2*q] += bflo(vv[q]); dd[2*q+1] += bfhi(vv[q]); }
        }
    }
    const float rs = 1.f / (sc > 0 ? (float)sc : 1.f);
    const float rd = 1.f / (dc > 0 ? (float)dc : 1.f);
    float4 a0v = *(const float4*)&ACCp[(size_t)a * FF + c8 * 8];
    float4 a1v = *(const float4*)&ACCp[(size_t)a * FF + c8 * 8 + 4];
    float ov[8] = {a0v.x, a0v.y, a0v.z, a0v.w, a1v.x, a1v.y, a1v.z, a1v.w};
    if (addAtoms) {
#pragma unroll
        for (int c = 0; c < NCAT; ++c) {
            float ac = sAt[at * NCAT + c];
            float4 w0 = *(const float4*)&sWv[c * FF + c8 * 8];
            float4 w1 = *(const float4*)&sWv[c * FF + c8 * 8 + 4];
            ov[0] = fmaf(ac, w0.x, ov[0]); ov[1] = fmaf(ac, w0.y, ov[1]);
            ov[2] = fmaf(ac, w0.z, ov[2]); ov[3] = fmaf(ac, w0.w, ov[3]);
            ov[4] = fmaf(ac, w1.x, ov[4]); ov[5] = fmaf(ac, w1.y, ov[5]);
            ov[6] = fmaf(ac, w1.z, ov[6]); ov[7] = fmaf(ac, w1.w, ov[7]);
        }
    }
    ushort8v zv;
#pragma unroll
    for (int e = 0; e < 8; ++e)
        zv[e] = bfc(fmaxf(fmaf(ss[e], rs, fmaf(dd[e], rd, ov[e])), 0.f));
    if (swizzle) {
        int ba = ((a >> 5) * 2 + (c8 >> 3)) * 4096
               + (((a & 31) * 128 + (c8 & 7) * 16) ^ ((a & 7) << 4));
        *(ushort8v*)((char*)Zp + ba) = zv;
    } else {
        *(ushort8v*)(Zp + (size_t)a * FF + c8 * 8) = zv;
    }
}

// ---------------------------------------------------------------------------
__global__ void k_resmean(const unsigned short* __restrict__ Zb, float* __restrict__ R12)
{
    const int p = blockIdx.y;
    const unsigned short* Zp = Zb + (size_t)p * 2048000;
    float* R = R12 + (size_t)p * 51200;
    int r = blockIdx.x, f = threadIdx.x;   // 128 threads
    float s = 0.f;
#pragma unroll 8
    for (int t = 0; t < APR; ++t) s += bfs(Zp[(size_t)(r * APR + t) * FF + f]);
    R[r * FF + f] = s * (1.0f / APR);
}

// ---------------------------------------------------------------------------
// A1[i] = r1[i] @ Wf1[:128,:] + bf1 ;  B1[j] = r2[j] @ Wf1[128:,:]
// ---------------------------------------------------------------------------
__global__ void k_pairprep(const float* __restrict__ R1, const float* __restrict__ R2,
                           const float* __restrict__ Wf1, const float* __restrict__ bf1,
                           float* __restrict__ A1, float* __restrict__ B1)
{
    __shared__ float r1s[FF], r2s[FF];
    int i = blockIdx.x, o = threadIdx.x;   // 256 threads
    if (o < FF) r1s[o] = R1[i * FF + o];
    else        r2s[o - FF] = R2[i * FF + (o - FF)];
    __syncthreads();
    float sa = bf1[o], sb = 0.f;
#pragma unroll 8
    for (int k = 0; k < FF; ++k) {
        sa = fmaf(r1s[k], Wf1[(size_t)k * DF1 + o], sa);
        sb = fmaf(r2s[k], Wf1[(size_t)(FF + k) * DF1 + o], sb);
    }
    A1[(size_t)i * DF1 + o] = sa;
    B1[(size_t)i * DF1 + o] = sb;
}

// ---------------------------------------------------------------------------
// Pair MLP via MFMA, register-built H (no H LDS round-trip, no inner barriers).
// ---------------------------------------------------------------------------
__global__ void __launch_bounds__(256)
k_pairs_mfma(const float* __restrict__ A1, const float* __restrict__ B1,
             const unsigned short* __restrict__ W2T,
             const float* __restrict__ bf2, const float* __restrict__ Wf3,
             const float* __restrict__ bf3, float* __restrict__ out)
{
    __shared__ __align__(16) float sA1[16 * 256];            // 16 KB linear
    __shared__ __align__(16) float sB1[16 * 256];            // 16 KB, XOR (row&7)<<5
    __shared__ __align__(16) unsigned short sW[64 * 256];    // 32 KB, XOR (n&7)<<4
    const int tid = threadIdx.x, l = tid & 63, w = tid >> 6;
    const int i0 = blockIdx.x * 16, j0 = blockIdx.y * 16;

    for (int idx = tid; idx < 64 * 32; idx += 256) {
        int row = idx >> 5, c = idx & 31;
        int ba = (row * 512 + c * 16) ^ ((row & 7) << 4);
        *(uint4*)((char*)sW + ba) = *(const uint4*)(W2T + row * 256 + c * 8);
    }
    {
        int row = tid >> 4;
#pragma unroll
        for (int pass = 0; pass < 4; ++pass) {
            int coff = pass * 64 + (tid & 15) * 4;
            *(float4*)((char*)sA1 + row * 1024 + coff * 4) =
                *(const float4*)&A1[(size_t)(i0 + row) * DF1 + coff];
            int bb = (row * 1024 + coff * 4) ^ ((row & 7) << 5);
            *(float4*)((char*)sB1 + bb) =
                *(const float4*)&B1[(size_t)(j0 + row) * DF1 + coff];
        }
    }
    __syncthreads();

    floatx4 acc[4][4];
#pragma unroll
    for (int mt = 0; mt < 4; ++mt)
#pragma unroll
        for (int nt = 0; nt < 4; ++nt) acc[mt][nt] = (floatx4){0.f, 0.f, 0.f, 0.f};

    float b2r[4], w3r[4];
#pragma unroll
    for (int nt = 0; nt < 4; ++nt) {
        b2r[nt] = bf2[nt * 16 + (l & 15)];
        w3r[nt] = Wf3[nt * 16 + (l & 15)];
    }

    const int rB = l & 15, kq = l >> 4;
#pragma unroll
    for (int kc = 0; kc < 4; ++kc)
#pragma unroll
        for (int ks = 0; ks < 2; ++ks) {
            const int kfb = (kc * 64 + ks * 32 + kq * 8) * 4;
            float4 b1a = *(const float4*)((char*)sB1 + ((rB * 1024 + kfb)      ^ ((rB & 7) << 5)));
            float4 b1b = *(const float4*)((char*)sB1 + ((rB * 1024 + kfb + 16) ^ ((rB & 7) << 5)));
            short8 afr[4];
#pragma unroll
            for (int mt = 0; mt < 4; ++mt) {
                int rA = w * 4 + mt;
                float4 a1a = *(const float4*)((char*)sA1 + rA * 1024 + kfb);
                float4 a1b = *(const float4*)((char*)sA1 + rA * 1024 + kfb + 16);
                short8 hv;
                hv[0] = (short)bfc(fmaxf(a1a.x + b1a.x, 0.f));
                hv[1] = (short)bfc(fmaxf(a1a.y + b1a.y, 0.f));
                hv[2] = (short)bfc(fmaxf(a1a.z + b1a.z, 0.f));
                hv[3] = (short)bfc(fmaxf(a1a.w + b1a.w, 0.f));
                hv[4] = (short)bfc(fmaxf(a1b.x + b1b.x, 0.f));
                hv[5] = (short)bfc(fmaxf(a1b.y + b1b.y, 0.f));
                hv[6] = (short)bfc(fmaxf(a1b.z + b1b.z, 0.f));
                hv[7] = (short)bfc(fmaxf(a1b.w + b1b.w, 0.f));
                afr[mt] = hv;
            }
            const int kwb = kc * 128 + ks * 64 + kq * 16;
            short8 bfr[4];
#pragma unroll
            for (int nt = 0; nt < 4; ++nt) {
                int n = nt * 16 + (l & 15);
                bfr[nt] = *(const short8*)((char*)sW + ((n * 512 + kwb) ^ ((n & 7) << 4)));
            }
#pragma unroll
            for (int mt = 0; mt < 4; ++mt)
#pragma unroll
                for (int nt = 0; nt < 4; ++nt)
                    acc[mt][nt] = __builtin_amdgcn_mfma_f32_16x16x32_bf16(afr[mt], bfr[nt], acc[mt][nt], 0, 0, 0);
        }

    const float b3 = bf3[0];
#pragma unroll
    for (int mt = 0; mt < 4; ++mt)
#pragma unroll
        for (int r = 0; r < 4; ++r) {
            float s = 0.f;
#pragma unroll
            for (int nt = 0; nt < 4; ++nt)
                s += fmaxf(acc[mt][nt][r] + b2r[nt], 0.f) * w3r[nt];
            s += __shfl_xor(s, 1); s += __shfl_xor(s, 2);
            s += __shfl_xor(s, 4); s += __shfl_xor(s, 8);
            if ((l & 15) == 0) {
                int p = w * 64 + mt * 16 + (l >> 4) * 4 + r;
                out[(size_t)(i0 + (p >> 4)) * NRES + j0 + (p & 15)] = s + b3;
            }
        }
}

// ---------------------------------------------------------------------------
extern "C" void kernel_launch(void* const* d_in, const int* in_sizes, int n_in,
                              void* d_out, int out_size, void* d_ws, size_t ws_size,
                              hipStream_t stream)
{
    const float* atoms0    = (const float*)d_in[0];
    const float* residues0 = (const float*)d_in[1];
    const int*   same0     = (const int*)d_in[2];
    const int*   diff0     = (const int*)d_in[3];
    const float* atoms1    = (const float*)d_in[5];
    const float* residues1 = (const float*)d_in[6];
    const int*   same1     = (const int*)d_in[7];
    const int*   diff1     = (const int*)d_in[8];
    const float* Wv   = (const float*)d_in[10];
    const float* Wr   = (const float*)d_in[11];
    const float* Wsr1 = (const float*)d_in[12];
    const float* Wdr1 = (const float*)d_in[13];
    const float* Wsv  = (const float*)d_in[14];
    const float* Wsr2 = (const float*)d_in[15];
    const float* Wdr2 = (const float*)d_in[16];
    const float* Wf1  = (const float*)d_in[17];
    const float* bf1  = (const float*)d_in[18];
    const float* Wf2  = (const float*)d_in[19];
    const float* bf2  = (const float*)d_in[20];
    const float* Wf3  = (const float*)d_in[21];
    const float* bf3  = (const float*)d_in[22];

    float* ws  = (float*)d_ws;
    float* ACC = ws;                                         // 2 x 2,048,000 f
    unsigned short* SD  = (unsigned short*)(ws + 4096000);   // 2 x 4,096,000 u16
    unsigned short* Zsw = (unsigned short*)(ws + 8192000);   // 2 x 2,048,000 u16
    unsigned short* Zb  = (unsigned short*)(ws + 10240000);  // 2 x 2,048,000 u16
    float* R12 = ws + 12288000;                              // 2 x 51,200 f
    float* A1  = ws + 12390400;                              // 102,400 f
    float* B1  = ws + 12492800;                              // 102,400 f
    unsigned short* WrT = (unsigned short*)(ws + 12595200);  // 131,072 u16
    unsigned short* Bt3 = (unsigned short*)(ws + 12660736);  //  49,152 u16
    unsigned short* W2T = (unsigned short*)(ws + 12685312);  //  16,384 u16

    k_prep<<<152, 256, 0, stream>>>(Wr, Wsv, Wsr2, Wdr2, Wf2, WrT, Bt3, W2T);
    k_atomsSD<<<dim3(NA / 2, 2), 256, 0, stream>>>(atoms0, atoms1, Wsr1, Wdr1, SD);
    k_gemm_big<<<dim3(NA / 64, 2), 256, 0, stream>>>(residues0, residues1, WrT, ACC);
    k_gather_relu<<<dim3(NA / 16, 2), 256, 0, stream>>>(ACC, SD, same0, diff0, same1, diff1,
                                                        atoms0, atoms1, Wv, Zsw, 1, 1);
    k_gemm_l2<<<dim3(NA / 32, 3, 2), 256, 0, stream>>>(Zsw, Bt3, ACC, SD);
    k_gather_relu<<<dim3(NA / 16, 2), 256, 0, stream>>>(ACC, SD, same0, diff0, same1, diff1,
                                                        atoms0, atoms1, Wv, Zb, 0, 0);
    k_resmean<<<dim3(NRES, 2), 128, 0, stream>>>(Zb, R12);
    k_pairprep<<<NRES, 256, 0, stream>>>(R12, R12 + 51200, Wf1, bf1, A1, B1);
    k_pairs_mfma<<<dim3(25, 25), 256, 0, stream>>>(A1, B1, W2T, bf2, Wf3, bf3, (float*)d_out);
}

// Round 7
// 133.126 us; speedup vs baseline: 4.9900x; 1.0941x over previous
//
#include <hip/hip_runtime.h>
#include <stdint.h>

#define NA   16000
#define KNN  10
#define NRES 400
#define APR  40
#define NCAT 12
#define BERT 1024
#define FF   128
#define DF1  256
#define DF2  64

using short8   = __attribute__((ext_vector_type(8))) short;
using floatx4  = __attribute__((ext_vector_type(4))) float;
using ushort4v = __attribute__((ext_vector_type(4))) unsigned short;
using ushort8v = __attribute__((ext_vector_type(8))) unsigned short;

__device__ __forceinline__ unsigned short bfc(float v) {
    return __builtin_bit_cast(unsigned short, (__bf16)v);
}
__device__ __forceinline__ float bflo(uint32_t u){ return __uint_as_float(u << 16); }
__device__ __forceinline__ float bfhi(uint32_t u){ return __uint_as_float(u & 0xffff0000u); }

// async global->LDS, 16B per lane
__device__ __forceinline__ void gload16(void* lds, const void* g) {
    __builtin_amdgcn_global_load_lds(
        (const __attribute__((address_space(1))) uint32_t*)g,
        (__attribute__((address_space(3))) uint32_t*)lds, 16, 0, 0);
}

// ---------------------------------------------------------------------------
// Weight prep.  WrT: 16 pre-swizzled 128x64 bf16 tiles (linear gload -> LDS
// image already XOR-swizzled); Bt3: 3 mats x 2 tiles; W2T: [64][256] bf16.
// ---------------------------------------------------------------------------
__global__ void k_prep(const float* __restrict__ Wr,
                       const float* __restrict__ Wsv, const float* __restrict__ Wsr2,
                       const float* __restrict__ Wdr2, const float* __restrict__ Wf2,
                       unsigned short* __restrict__ WrT, unsigned short* __restrict__ Bt3,
                       unsigned short* __restrict__ W2T)
{
    int idx = blockIdx.x * 256 + threadIdx.x;
    if (idx < 16384) {
        int t = idx >> 10, rem = idx & 1023, n = rem >> 3, kq = rem & 7;
        ushort8v v;
#pragma unroll
        for (int e = 0; e < 8; ++e)
            v[e] = bfc(Wr[(size_t)(t * 64 + kq * 8 + e) * FF + n]);
        int ba = t * 16384 + ((n * 128 + kq * 16) ^ ((n & 7) << 4));
        *(ushort8v*)((char*)WrT + ba) = v;
    } else if (idx < 16384 + 6144) {
        int i2 = idx - 16384;
        int m = i2 >> 11, r2 = i2 & 2047;
        int t = r2 >> 10, r3 = r2 & 1023, n = r3 >> 3, kq = r3 & 7;
        const float* W = (m == 0) ? Wsv : ((m == 1) ? Wsr2 : Wdr2);
        ushort8v v;
#pragma unroll
        for (int e = 0; e < 8; ++e)
            v[e] = bfc(W[(size_t)(t * 64 + kq * 8 + e) * FF + n]);
        int ba = (m * 2 + t) * 16384 + ((n * 128 + kq * 16) ^ ((n & 7) << 4));
        *(ushort8v*)((char*)Bt3 + ba) = v;
    } else {
        int i3 = idx - 16384 - 6144;
        int n = i3 >> 8, k = i3 & 255;
        W2T[i3] = bfc(Wf2[(size_t)k * DF2 + n]);
    }
}

// ---------------------------------------------------------------------------
// SD[a][0:128]=bf16(atoms@Wsr1), [128:256]=bf16(atoms@Wdr1).
// 64 atoms/block; weights in registers, atom rows staged in LDS.
// ---------------------------------------------------------------------------
__global__ void __launch_bounds__(256)
k_atomsSD(const float* __restrict__ atoms0, const float* __restrict__ atoms1,
          const float* __restrict__ Wsr1, const float* __restrict__ Wdr1,
          unsigned short* __restrict__ SD)
{
    __shared__ float sAt[64 * NCAT];   // 3 KB
    const int p = blockIdx.y;
    const float* atoms = p ? atoms1 : atoms0;
    unsigned short* SDp = SD + (size_t)p * 4096000;
    const int a0 = blockIdx.x * 64;
    const int tid = threadIdx.x;
    const int f = tid & 127, half = tid >> 7;

    if (tid < 192)
        ((float4*)sAt)[tid] = *(const float4*)&atoms[(size_t)a0 * NCAT + tid * 4];

    float wsr[NCAT], wdr[NCAT];
#pragma unroll
    for (int c = 0; c < NCAT; ++c) {
        wsr[c] = Wsr1[c * FF + f];
        wdr[c] = Wdr1[c * FF + f];
    }
    __syncthreads();

#pragma unroll 4
    for (int pass = 0; pass < 32; ++pass) {
        int ai = pass * 2 + half;
        int a = a0 + ai;
        float ss = 0.f, sd = 0.f;
#pragma unroll
        for (int c = 0; c < NCAT; ++c) {
            float ac = sAt[ai * NCAT + c];
            ss = fmaf(ac, wsr[c], ss);
            sd = fmaf(ac, wdr[c], sd);
        }
        SDp[(size_t)a * 256 + f]       = bfc(ss);
        SDp[(size_t)a * 256 + 128 + f] = bfc(sd);
    }
}

// ---------------------------------------------------------------------------
// Big GEMM: residues[16000,1024] @ Wr -> ACC[16000,128] fp32.
// BM=32 (grid 1000 -> ~4 blocks/CU), single-buffered, plain 2-barrier loop.
// A staged fp32 via global_load_lds with PRE-SWIZZLED SOURCE addresses:
// LDS[(row*256+cb) ^ ((row&7)<<4)] = A[row][cb] (XOR stays within the row).
// B from pre-swizzled global (linear gload).  bf16 convert after ds_read.
// ---------------------------------------------------------------------------
__global__ void __launch_bounds__(256, 4)
k_gemm_big(const float* __restrict__ R0, const float* __restrict__ R1,
           const unsigned short* __restrict__ Bsw, float* __restrict__ OUT)
{
    __shared__ __align__(16) float sA[32 * 64];              //  8 KB swizzled fp32
    __shared__ __align__(16) unsigned short sB[128 * 64];    // 16 KB pre-swizzled bf16
    const int tid = threadIdx.x, l = tid & 63, w = tid >> 6;
    const int m0 = blockIdx.x * 32;
    const float* A = blockIdx.y ? R1 : R0;
    float* C = OUT + (size_t)blockIdx.y * 2048000;

    floatx4 acc[2][2];
#pragma unroll
    for (int mt = 0; mt < 2; ++mt)
#pragma unroll
        for (int nt = 0; nt < 2; ++nt) acc[mt][nt] = (floatx4){0.f, 0.f, 0.f, 0.f};

    const int arow = tid >> 4;                                   // 0..15
    const int aswz = ((tid & 15) * 16) ^ ((arow & 7) << 4);      // swizzled byte-in-row

    for (int t = 0; t < 16; ++t) {
        if (t) __syncthreads();
        // stage A (2 gloads, swizzled source)
#pragma unroll
        for (int pp = 0; pp < 2; ++pp) {
            int row = pp * 16 + arow;   // row&7 == arow&7
            gload16((char*)sA + pp * 4096 + tid * 16,
                    (const char*)A + (size_t)(m0 + row) * 4096 + (size_t)t * 256 + aswz);
        }
        // stage B (4 gloads, linear; content pre-swizzled)
        {
            const char* bs = (const char*)Bsw + (size_t)t * 16384 + tid * 16;
#pragma unroll
            for (int q = 0; q < 4; ++q) gload16((char*)sB + tid * 16 + q * 4096, bs + q * 4096);
        }
        __syncthreads();
        // compute
#pragma unroll
        for (int ks = 0; ks < 2; ++ks) {
            short8 ah[2], bh[2];
#pragma unroll
            for (int mt = 0; mt < 2; ++mt) {
                int row = mt * 16 + (l & 15);
                int cb = ks * 128 + (l >> 4) * 32;
                int sw = (row & 7) << 4;
                float4 f0 = *(const float4*)((char*)sA + ((row * 256 + cb) ^ sw));
                float4 f1 = *(const float4*)((char*)sA + ((row * 256 + cb + 16) ^ sw));
                short8 hv;
                hv[0] = (short)bfc(f0.x); hv[1] = (short)bfc(f0.y);
                hv[2] = (short)bfc(f0.z); hv[3] = (short)bfc(f0.w);
                hv[4] = (short)bfc(f1.x); hv[5] = (short)bfc(f1.y);
                hv[6] = (short)bfc(f1.z); hv[7] = (short)bfc(f1.w);
                ah[mt] = hv;
            }
#pragma unroll
            for (int nt = 0; nt < 2; ++nt) {
                int row = w * 32 + nt * 16 + (l & 15);
                int kb = ks * 64 + (l >> 4) * 16;
                bh[nt] = *(const short8*)((char*)sB + ((row * 128 + kb) ^ ((row & 7) << 4)));
            }
#pragma unroll
            for (int mt = 0; mt < 2; ++mt)
#pragma unroll
                for (int nt = 0; nt < 2; ++nt)
                    acc[mt][nt] = __builtin_amdgcn_mfma_f32_16x16x32_bf16(ah[mt], bh[nt], acc[mt][nt], 0, 0, 0);
        }
    }

#pragma unroll
    for (int mt = 0; mt < 2; ++mt)
#pragma unroll
        for (int nt = 0; nt < 2; ++nt)
#pragma unroll
            for (int r = 0; r < 4; ++r) {
                int row = m0 + mt * 16 + (l >> 4) * 4 + r;
                int col = w * 32 + nt * 16 + (l & 15);
                C[(size_t)row * FF + col] = acc[mt][nt][r];
            }
}

// ---------------------------------------------------------------------------
// Layer-2 GEMM: Z(pre-swizzled bf16 tiles) @ {Wsv,Wsr2,Wdr2}.  K=128, both
// k-tiles staged up-front (single barrier).  blockIdx: x=m, y=mat, z=protein.
// ---------------------------------------------------------------------------
__global__ void __launch_bounds__(256)
k_gemm_l2(const unsigned short* __restrict__ Zsw, const unsigned short* __restrict__ Bt3,
          float* __restrict__ ACC, unsigned short* __restrict__ SD)
{
    __shared__ __align__(16) unsigned short sA[2][32 * 64];   // 2 x 4 KB
    __shared__ __align__(16) unsigned short sB[2][128 * 64];  // 2 x 16 KB
    const int tid = threadIdx.x, l = tid & 63, w = tid >> 6;
    const int m0 = blockIdx.x * 32;
    const int mat = blockIdx.y, p = blockIdx.z;
    const unsigned short* Zp = Zsw + (size_t)p * 2048000;

    floatx4 acc[2][2];
#pragma unroll
    for (int mt = 0; mt < 2; ++mt)
#pragma unroll
        for (int nt = 0; nt < 2; ++nt) acc[mt][nt] = (floatx4){0.f, 0.f, 0.f, 0.f};

#pragma unroll
    for (int t = 0; t < 2; ++t) {
        const char* bs = (const char*)Bt3 + (size_t)(mat * 2 + t) * 16384 + tid * 16;
#pragma unroll
        for (int q = 0; q < 4; ++q) gload16((char*)sB[t] + tid * 16 + q * 4096, bs + q * 4096);
        gload16((char*)sA[t] + tid * 16,
                (const char*)Zp + (size_t)((m0 >> 5) * 2 + t) * 4096 + tid * 16);
    }
    __syncthreads();

#pragma unroll
    for (int t = 0; t < 2; ++t)
#pragma unroll
        for (int ks = 0; ks < 2; ++ks) {
            short8 ah[2], bh[2];
            const int kb = ks * 64 + (l >> 4) * 16;
#pragma unroll
            for (int mt = 0; mt < 2; ++mt) {
                int row = mt * 16 + (l & 15);
                ah[mt] = *(const short8*)((char*)sA[t] + ((row * 128 + kb) ^ ((row & 7) << 4)));
            }
#pragma unroll
            for (int nt = 0; nt < 2; ++nt) {
                int row = w * 32 + nt * 16 + (l & 15);
                bh[nt] = *(const short8*)((char*)sB[t] + ((row * 128 + kb) ^ ((row & 7) << 4)));
            }
#pragma unroll
            for (int mt = 0; mt < 2; ++mt)
#pragma unroll
                for (int nt = 0; nt < 2; ++nt)
                    acc[mt][nt] = __builtin_amdgcn_mfma_f32_16x16x32_bf16(ah[mt], bh[nt], acc[mt][nt], 0, 0, 0);
        }

    float* ACCp = ACC + (size_t)p * 2048000;
    unsigned short* SDp = (unsigned short*)SD + (size_t)p * 4096000;
#pragma unroll
    for (int mt = 0; mt < 2; ++mt)
#pragma unroll
        for (int nt = 0; nt < 2; ++nt)
#pragma unroll
            for (int r = 0; r < 4; ++r) {
                int row = m0 + mt * 16 + (l >> 4) * 4 + r;
                int col = w * 32 + nt * 16 + (l & 15);
                float v = acc[mt][nt][r];
                if (mat == 0) ACCp[(size_t)row * FF + col] = v;
                else          SDp [(size_t)row * 256 + (mat - 1) * FF + col] = bfc(v);
            }
}

// ---------------------------------------------------------------------------
// Gather 1: Z = relu(ACC + atoms@Wv + mean(S,sn) + mean(D,dn)) -> Zsw
// (bf16, pre-swizzled tiles for k_gemm_l2's A staging).
// ---------------------------------------------------------------------------
__global__ void __launch_bounds__(256)
k_gather1(const float* __restrict__ ACC, const unsigned short* __restrict__ SD,
          const int* __restrict__ sn0, const int* __restrict__ dn0,
          const int* __restrict__ sn1, const int* __restrict__ dn1,
          const float* __restrict__ atoms0, const float* __restrict__ atoms1,
          const float* __restrict__ Wv, unsigned short* __restrict__ Zout)
{
    __shared__ int sIdx[16][20];
    __shared__ float sWv[NCAT * FF];   // 6 KB
    __shared__ float sAt[16 * NCAT];   // 768 B
    const int tid = threadIdx.x;
    const int p = blockIdx.y;
    const int a0 = blockIdx.x * 16;
    const int* sn = p ? sn1 : sn0;
    const int* dn = p ? dn1 : dn0;
    const float* ACCp = ACC + (size_t)p * 2048000;
    const unsigned short* SDp = SD + (size_t)p * 4096000;
    unsigned short* Zp = Zout + (size_t)p * 2048000;

    for (int t = tid; t < 320; t += 256) {
        int at = t / 20, q = t - at * 20;
        sIdx[at][q] = (q < 10) ? sn[(a0 + at) * KNN + q] : dn[(a0 + at) * KNN + q - 10];
    }
    {
        const float* atoms = p ? atoms1 : atoms0;
        for (int i = tid; i < 384; i += 256)
            ((float4*)sWv)[i] = ((const float4*)Wv)[i];
        if (tid < 48) {
            int at = tid / 3, q = tid - at * 3;
            *(float4*)&sAt[at * NCAT + q * 4] =
                *(const float4*)&atoms[(size_t)(a0 + at) * NCAT + q * 4];
        }
    }
    __syncthreads();
    const int at = tid >> 4, c8 = tid & 15;
    const int a = a0 + at;
    float ss[8] = {0,0,0,0,0,0,0,0}, dd[8] = {0,0,0,0,0,0,0,0};
    int sc = 0, dc = 0;
#pragma unroll
    for (int n = 0; n < KNN; ++n) {
        int is = sIdx[at][n];
        if (is > -1) {
            sc++;
            uint4 v = *(const uint4*)&SDp[(size_t)is * 256 + c8 * 8];
            uint32_t vv[4] = {v.x, v.y, v.z, v.w};
#pragma unroll
            for (int q = 0; q < 4; ++q) { ss[2*q] += bflo(vv[q]); ss[2*q+1] += bfhi(vv[q]); }
        }
    }
#pragma unroll
    for (int n = 0; n < KNN; ++n) {
        int id = sIdx[at][10 + n];
        if (id > -1) {
            dc++;
            uint4 v = *(const uint4*)&SDp[(size_t)id * 256 + 128 + c8 * 8];
            uint32_t vv[4] = {v.x, v.y, v.z, v.w};
#pragma unroll
            for (int q = 0; q < 4; ++q) { dd[2*q] += bflo(vv[q]); dd[2*q+1] += bfhi(vv[q]); }
        }
    }
    const float rs = 1.f / (sc > 0 ? (float)sc : 1.f);
    const float rd = 1.f / (dc > 0 ? (float)dc : 1.f);
    float4 a0v = *(const float4*)&ACCp[(size_t)a * FF + c8 * 8];
    float4 a1v = *(const float4*)&ACCp[(size_t)a * FF + c8 * 8 + 4];
    float ov[8] = {a0v.x, a0v.y, a0v.z, a0v.w, a1v.x, a1v.y, a1v.z, a1v.w};
#pragma unroll
    for (int c = 0; c < NCAT; ++c) {
        float ac = sAt[at * NCAT + c];
        float4 w0 = *(const float4*)&sWv[c * FF + c8 * 8];
        float4 w1 = *(const float4*)&sWv[c * FF + c8 * 8 + 4];
        ov[0] = fmaf(ac, w0.x, ov[0]); ov[1] = fmaf(ac, w0.y, ov[1]);
        ov[2] = fmaf(ac, w0.z, ov[2]); ov[3] = fmaf(ac, w0.w, ov[3]);
        ov[4] = fmaf(ac, w1.x, ov[4]); ov[5] = fmaf(ac, w1.y, ov[5]);
        ov[6] = fmaf(ac, w1.z, ov[6]); ov[7] = fmaf(ac, w1.w, ov[7]);
    }
    ushort8v zv;
#pragma unroll
    for (int e = 0; e < 8; ++e)
        zv[e] = bfc(fmaxf(fmaf(ss[e], rs, fmaf(dd[e], rd, ov[e])), 0.f));
    int ba = ((a >> 5) * 2 + (c8 >> 3)) * 4096
           + (((a & 31) * 128 + (c8 & 7) * 16) ^ ((a & 7) << 4));
    *(ushort8v*)((char*)Zp + ba) = zv;
}

// ---------------------------------------------------------------------------
// Gather 2 fused with residue mean: one block per residue (40 atoms).
// R[r] = mean_a relu(ACC[a] + mean(S,sn) + mean(D,dn)).
// ---------------------------------------------------------------------------
__global__ void __launch_bounds__(256)
k_gather_res(const float* __restrict__ ACC, const unsigned short* __restrict__ SD,
             const int* __restrict__ sn0, const int* __restrict__ dn0,
             const int* __restrict__ sn1, const int* __restrict__ dn1,
             float* __restrict__ R12)
{
    __shared__ int sIdx[APR][20];      // 3.2 KB
    __shared__ float zpart[16][128];   // 8 KB
    const int tid = threadIdx.x;
    const int p = blockIdx.y, r = blockIdx.x;
    const int* sn = p ? sn1 : sn0;
    const int* dn = p ? dn1 : dn0;
    const float* ACCp = ACC + (size_t)p * 2048000;
    const unsigned short* SDp = SD + (size_t)p * 4096000;
    const int aBase = r * APR;

    for (int t = tid; t < APR * 20; t += 256) {
        int at = t / 20, q = t - at * 20;
        sIdx[at][q] = (q < 10) ? sn[(aBase + at) * KNN + q] : dn[(aBase + at) * KNN + q - 10];
    }
    __syncthreads();

    const int at = tid >> 4, c8 = tid & 15;
    float zs[8] = {0,0,0,0,0,0,0,0};
#pragma unroll
    for (int rep = 0; rep < 3; ++rep) {
        int ai = at + rep * 16;
        if (ai < APR) {
            int a = aBase + ai;
            float ss[8] = {0,0,0,0,0,0,0,0}, dd[8] = {0,0,0,0,0,0,0,0};
            int sc = 0, dc = 0;
#pragma unroll
            for (int n = 0; n < KNN; ++n) {
                int is = sIdx[ai][n];
                if (is > -1) {
                    sc++;
                    uint4 v = *(const uint4*)&SDp[(size_t)is * 256 + c8 * 8];
                    uint32_t vv[4] = {v.x, v.y, v.z, v.w};
#pragma unroll
                    for (int q = 0; q < 4; ++q) { ss[2*q] += bflo(vv[q]); ss[2*q+1] += bfhi(vv[q]); }
                }
            }
#pragma unroll
            for (int n = 0; n < KNN; ++n) {
                int id = sIdx[ai][10 + n];
                if (id > -1) {
                    dc++;
                    uint4 v = *(const uint4*)&SDp[(size_t)id * 256 + 128 + c8 * 8];
                    uint32_t vv[4] = {v.x, v.y, v.z, v.w};
#pragma unroll
                    for (int q = 0; q < 4; ++q) { dd[2*q] += bflo(vv[q]); dd[2*q+1] += bfhi(vv[q]); }
                }
            }
            const float rs = 1.f / (sc > 0 ? (float)sc : 1.f);
            const float rd = 1.f / (dc > 0 ? (float)dc : 1.f);
            float4 a0v = *(const float4*)&ACCp[(size_t)a * FF + c8 * 8];
            float4 a1v = *(const float4*)&ACCp[(size_t)a * FF + c8 * 8 + 4];
            float ov[8] = {a0v.x, a0v.y, a0v.z, a0v.w, a1v.x, a1v.y, a1v.z, a1v.w};
#pragma unroll
            for (int e = 0; e < 8; ++e)
                zs[e] += fmaxf(fmaf(ss[e], rs, fmaf(dd[e], rd, ov[e])), 0.f);
        }
    }
    *(float4*)&zpart[at][c8 * 8]     = (float4){zs[0], zs[1], zs[2], zs[3]};
    *(float4*)&zpart[at][c8 * 8 + 4] = (float4){zs[4], zs[5], zs[6], zs[7]};
    __syncthreads();
#pragma unroll
    for (int s = 8; s > 0; s >>= 1) {
        if (at < s) {
            float4 x0 = *(const float4*)&zpart[at + s][c8 * 8];
            float4 x1 = *(const float4*)&zpart[at + s][c8 * 8 + 4];
            float4 y0 = *(const float4*)&zpart[at][c8 * 8];
            float4 y1 = *(const float4*)&zpart[at][c8 * 8 + 4];
            y0.x += x0.x; y0.y += x0.y; y0.z += x0.z; y0.w += x0.w;
            y1.x += x1.x; y1.y += x1.y; y1.z += x1.z; y1.w += x1.w;
            *(float4*)&zpart[at][c8 * 8]     = y0;
            *(float4*)&zpart[at][c8 * 8 + 4] = y1;
        }
        __syncthreads();
    }
    if (at == 0) {
        float* R = R12 + (size_t)p * 51200 + (size_t)r * FF;
        const float inv = 1.0f / APR;
#pragma unroll
        for (int e = 0; e < 8; ++e) R[c8 * 8 + e] = zpart[0][c8 * 8 + e] * inv;
    }
}

// ---------------------------------------------------------------------------
// A1[i] = r1[i] @ Wf1[:128,:] + bf1 ;  B1[j] = r2[j] @ Wf1[128:,:]
// ---------------------------------------------------------------------------
__global__ void k_pairprep(const float* __restrict__ R1, const float* __restrict__ R2,
                           const float* __restrict__ Wf1, const float* __restrict__ bf1,
                           float* __restrict__ A1, float* __restrict__ B1)
{
    __shared__ float r1s[FF], r2s[FF];
    int i = blockIdx.x, o = threadIdx.x;   // 256 threads
    if (o < FF) r1s[o] = R1[i * FF + o];
    else        r2s[o - FF] = R2[i * FF + (o - FF)];
    __syncthreads();
    float sa = bf1[o], sb = 0.f;
#pragma unroll 8
    for (int k = 0; k < FF; ++k) {
        sa = fmaf(r1s[k], Wf1[(size_t)k * DF1 + o], sa);
        sb = fmaf(r2s[k], Wf1[(size_t)(FF + k) * DF1 + o], sb);
    }
    A1[(size_t)i * DF1 + o] = sa;
    B1[(size_t)i * DF1 + o] = sb;
}

// ---------------------------------------------------------------------------
// Pair MLP via MFMA, register-built H (no H LDS round-trip, no inner barriers).
// ---------------------------------------------------------------------------
__global__ void __launch_bounds__(256)
k_pairs_mfma(const float* __restrict__ A1, const float* __restrict__ B1,
             const unsigned short* __restrict__ W2T,
             const float* __restrict__ bf2, const float* __restrict__ Wf3,
             const float* __restrict__ bf3, float* __restrict__ out)
{
    __shared__ __align__(16) float sA1[16 * 256];            // 16 KB linear
    __shared__ __align__(16) float sB1[16 * 256];            // 16 KB, XOR (row&7)<<5
    __shared__ __align__(16) unsigned short sW[64 * 256];    // 32 KB, XOR (n&7)<<4
    const int tid = threadIdx.x, l = tid & 63, w = tid >> 6;
    const int i0 = blockIdx.x * 16, j0 = blockIdx.y * 16;

    for (int idx = tid; idx < 64 * 32; idx += 256) {
        int row = idx >> 5, c = idx & 31;
        int ba = (row * 512 + c * 16) ^ ((row & 7) << 4);
        *(uint4*)((char*)sW + ba) = *(const uint4*)(W2T + row * 256 + c * 8);
    }
    {
        int row = tid >> 4;
#pragma unroll
        for (int pass = 0; pass < 4; ++pass) {
            int coff = pass * 64 + (tid & 15) * 4;
            *(float4*)((char*)sA1 + row * 1024 + coff * 4) =
                *(const float4*)&A1[(size_t)(i0 + row) * DF1 + coff];
            int bb = (row * 1024 + coff * 4) ^ ((row & 7) << 5);
            *(float4*)((char*)sB1 + bb) =
                *(const float4*)&B1[(size_t)(j0 + row) * DF1 + coff];
        }
    }
    __syncthreads();

    floatx4 acc[4][4];
#pragma unroll
    for (int mt = 0; mt < 4; ++mt)
#pragma unroll
        for (int nt = 0; nt < 4; ++nt) acc[mt][nt] = (floatx4){0.f, 0.f, 0.f, 0.f};

    float b2r[4], w3r[4];
#pragma unroll
    for (int nt = 0; nt < 4; ++nt) {
        b2r[nt] = bf2[nt * 16 + (l & 15)];
        w3r[nt] = Wf3[nt * 16 + (l & 15)];
    }

    const int rB = l & 15, kq = l >> 4;
#pragma unroll
    for (int kc = 0; kc < 4; ++kc)
#pragma unroll
        for (int ks = 0; ks < 2; ++ks) {
            const int kfb = (kc * 64 + ks * 32 + kq * 8) * 4;
            float4 b1a = *(const float4*)((char*)sB1 + ((rB * 1024 + kfb)      ^ ((rB & 7) << 5)));
            float4 b1b = *(const float4*)((char*)sB1 + ((rB * 1024 + kfb + 16) ^ ((rB & 7) << 5)));
            short8 afr[4];
#pragma unroll
            for (int mt = 0; mt < 4; ++mt) {
                int rA = w * 4 + mt;
                float4 a1a = *(const float4*)((char*)sA1 + rA * 1024 + kfb);
                float4 a1b = *(const float4*)((char*)sA1 + rA * 1024 + kfb + 16);
                short8 hv;
                hv[0] = (short)bfc(fmaxf(a1a.x + b1a.x, 0.f));
                hv[1] = (short)bfc(fmaxf(a1a.y + b1a.y, 0.f));
                hv[2] = (short)bfc(fmaxf(a1a.z + b1a.z, 0.f));
                hv[3] = (short)bfc(fmaxf(a1a.w + b1a.w, 0.f));
                hv[4] = (short)bfc(fmaxf(a1b.x + b1b.x, 0.f));
                hv[5] = (short)bfc(fmaxf(a1b.y + b1b.y, 0.f));
                hv[6] = (short)bfc(fmaxf(a1b.z + b1b.z, 0.f));
                hv[7] = (short)bfc(fmaxf(a1b.w + b1b.w, 0.f));
                afr[mt] = hv;
            }
            const int kwb = kc * 128 + ks * 64 + kq * 16;
            short8 bfr[4];
#pragma unroll
            for (int nt = 0; nt < 4; ++nt) {
                int n = nt * 16 + (l & 15);
                bfr[nt] = *(const short8*)((char*)sW + ((n * 512 + kwb) ^ ((n & 7) << 4)));
            }
#pragma unroll
            for (int mt = 0; mt < 4; ++mt)
#pragma unroll
                for (int nt = 0; nt < 4; ++nt)
                    acc[mt][nt] = __builtin_amdgcn_mfma_f32_16x16x32_bf16(afr[mt], bfr[nt], acc[mt][nt], 0, 0, 0);
        }

    const float b3 = bf3[0];
#pragma unroll
    for (int mt = 0; mt < 4; ++mt)
#pragma unroll
        for (int r = 0; r < 4; ++r) {
            float s = 0.f;
#pragma unroll
            for (int nt = 0; nt < 4; ++nt)
                s += fmaxf(acc[mt][nt][r] + b2r[nt], 0.f) * w3r[nt];
            s += __shfl_xor(s, 1); s += __shfl_xor(s, 2);
            s += __shfl_xor(s, 4); s += __shfl_xor(s, 8);
            if ((l & 15) == 0) {
                int p = w * 64 + mt * 16 + (l >> 4) * 4 + r;
                out[(size_t)(i0 + (p >> 4)) * NRES + j0 + (p & 15)] = s + b3;
            }
        }
}

// ---------------------------------------------------------------------------
extern "C" void kernel_launch(void* const* d_in, const int* in_sizes, int n_in,
                              void* d_out, int out_size, void* d_ws, size_t ws_size,
                              hipStream_t stream)
{
    const float* atoms0    = (const float*)d_in[0];
    const float* residues0 = (const float*)d_in[1];
    const int*   same0     = (const int*)d_in[2];
    const int*   diff0     = (const int*)d_in[3];
    const float* atoms1    = (const float*)d_in[5];
    const float* residues1 = (const float*)d_in[6];
    const int*   same1     = (const int*)d_in[7];
    const int*   diff1     = (const int*)d_in[8];
    const float* Wv   = (const float*)d_in[10];
    const float* Wr   = (const float*)d_in[11];
    const float* Wsr1 = (const float*)d_in[12];
    const float* Wdr1 = (const float*)d_in[13];
    const float* Wsv  = (const float*)d_in[14];
    const float* Wsr2 = (const float*)d_in[15];
    const float* Wdr2 = (const float*)d_in[16];
    const float* Wf1  = (const float*)d_in[17];
    const float* bf1  = (const float*)d_in[18];
    const float* Wf2  = (const float*)d_in[19];
    const float* bf2  = (const float*)d_in[20];
    const float* Wf3  = (const float*)d_in[21];
    const float* bf3  = (const float*)d_in[22];

    float* ws  = (float*)d_ws;
    float* ACC = ws;                                         // 2 x 2,048,000 f
    unsigned short* SD  = (unsigned short*)(ws + 4096000);   // 2 x 4,096,000 u16
    unsigned short* Zsw = (unsigned short*)(ws + 8192000);   // 2 x 2,048,000 u16
    float* R12 = ws + 10240000;                              // 2 x 51,200 f
    float* A1  = ws + 10342400;                              // 102,400 f
    float* B1  = ws + 10444800;                              // 102,400 f
    unsigned short* WrT = (unsigned short*)(ws + 10547200);  // 131,072 u16
    unsigned short* Bt3 = (unsigned short*)(ws + 10612736);  //  49,152 u16
    unsigned short* W2T = (unsigned short*)(ws + 10637312);  //  16,384 u16

    k_prep<<<152, 256, 0, stream>>>(Wr, Wsv, Wsr2, Wdr2, Wf2, WrT, Bt3, W2T);
    k_atomsSD<<<dim3(NA / 64, 2), 256, 0, stream>>>(atoms0, atoms1, Wsr1, Wdr1, SD);
    k_gemm_big<<<dim3(NA / 32, 2), 256, 0, stream>>>(residues0, residues1, WrT, ACC);
    k_gather1<<<dim3(NA / 16, 2), 256, 0, stream>>>(ACC, SD, same0, diff0, same1, diff1,
                                                    atoms0, atoms1, Wv, Zsw);
    k_gemm_l2<<<dim3(NA / 32, 3, 2), 256, 0, stream>>>(Zsw, Bt3, ACC, SD);
    k_gather_res<<<dim3(NRES, 2), 256, 0, stream>>>(ACC, SD, same0, diff0, same1, diff1, R12);
    k_pairprep<<<NRES, 256, 0, stream>>>(R12, R12 + 51200, Wf1, bf1, A1, B1);
    k_pairs_mfma<<<dim3(25, 25), 256, 0, stream>>>(A1, B1, W2T, bf2, Wf3, bf3, (float*)d_out);
}